// Round 8
// baseline (440.603 us; speedup 1.0000x reference)
//
#include <hip/hip_runtime.h>
#include <math.h>

#define TIME_N 65536
#define HALFN  1024
#define NBINS  1025
#define NFRAMES 64
#define FCHUNK 8
#define NCHUNK (NFRAMES / FCHUNK)   // 8

// ---------------------------------------------------------------------------
// Kernel 1: channel mixing  out[b,d,t] = sum_c x[b,c,t] * M[c,d]
// ---------------------------------------------------------------------------
#define TT 128
__global__ __launch_bounds__(256) void mix_kernel(const float* __restrict__ x,
                                                  const float* __restrict__ M,
                                                  float* __restrict__ out) {
    __shared__ float Ml[64 * 64];
    __shared__ float xt[64][136];
    const int b   = blockIdx.y;
    const int t0  = blockIdx.x * TT;
    const int tid = threadIdx.x;

    for (int i = tid; i < 64 * 64; i += 256) Ml[i] = M[i];

    for (int r = 0; r < 8; ++r) {
        int fi = tid + r * 256;
        int c  = fi >> 5;
        int t4 = fi & 31;
        float4 v = *reinterpret_cast<const float4*>(
            x + (size_t)(b * 64 + c) * TIME_N + t0 + t4 * 4);
        *reinterpret_cast<float4*>(&xt[c][t4 * 4]) = v;
    }
    __syncthreads();

    const int dq = tid >> 5;
    const int tq = tid & 31;

    float acc[8][4];
#pragma unroll
    for (int i = 0; i < 8; ++i)
#pragma unroll
        for (int j = 0; j < 4; ++j) acc[i][j] = 0.f;

    for (int c = 0; c < 64; ++c) {
        float xv[4];
#pragma unroll
        for (int j = 0; j < 4; ++j) xv[j] = xt[c][tq + 32 * j];
#pragma unroll
        for (int i = 0; i < 8; ++i) {
            float mv = Ml[c * 64 + dq * 8 + i];
#pragma unroll
            for (int j = 0; j < 4; ++j) acc[i][j] += xv[j] * mv;
        }
    }

#pragma unroll
    for (int i = 0; i < 8; ++i) {
        int d = dq * 8 + i;
        size_t baseo = (size_t)(b * 64 + d) * TIME_N + t0;
#pragma unroll
        for (int j = 0; j < 4; ++j) out[baseo + tq + 32 * j] = acc[i][j];
    }
}

// ---------------------------------------------------------------------------
// Kernel 2: fused STFT -> per-bin frame recursion -> iSTFT -> OLA -> tanh.
// 256 blocks x 512 threads (512-thread WGs get a 128-VGPR budget; 1024-thread
// WGs are capped at 64 and spill -- measured R2-R7). FCHUNK=8: 8 FFTs x 64
// lanes, 4 radix-4 butterflies/thread. Ping-pong Stockham, 1 barrier/stage.
// Forward stage 0 is fused with the global load + Hann window (coalesced).
// 12 barriers per 8-frame chunk (96 total, vs 224 in R7).
// ---------------------------------------------------------------------------
__device__ __forceinline__ int P(int i) { return i + (i >> 4); }   // pad-16
#define BUFSZ 1088   // P(1023) = 1086

__device__ __forceinline__ float2 cadd(float2 a, float2 b){return make_float2(a.x+b.x, a.y+b.y);}
__device__ __forceinline__ float2 csub(float2 a, float2 b){return make_float2(a.x-b.x, a.y-b.y);}
__device__ __forceinline__ float2 cmul(float2 a, float2 b){return make_float2(a.x*b.x - a.y*b.y, a.x*b.y + a.y*b.x);}

// Generic radix-4 self-sorting Stockham stage (ping-pong). lt in [0,64):
// butterflies i = lt + r*64, r = 0..3.  k = stage index.
template<int SGN>
__device__ __forceinline__ void fft_stage(const float2* __restrict__ src,
                                          float2* __restrict__ dst,
                                          int lt, int k) {
    const float PI2 = 6.2831853071795864769f;
    const int s = 1 << (2 * k);
    const int n = 1024 >> (2 * k);
#pragma unroll
    for (int r = 0; r < 4; ++r) {
        const int i = lt + r * 64;
        const int p = i >> (2 * k);
        const int q = i & (s - 1);
        float2 a  = src[P(i)];
        float2 bv = src[P(i + 256)];
        float2 cv = src[P(i + 512)];
        float2 dv = src[P(i + 768)];
        float ang = (float)SGN * PI2 * (float)p / (float)n;
        float sn, cs; __sincosf(ang, &sn, &cs);
        float2 w1 = make_float2(cs, sn);
        float2 w2 = cmul(w1, w1);
        float2 w3 = cmul(w1, w2);
        float2 apc = cadd(a, cv), amc = csub(a, cv);
        float2 bpd = cadd(bv, dv), bmd = csub(bv, dv);
        float2 sj = make_float2(-(float)SGN * bmd.y, (float)SGN * bmd.x);
        float2 y0 = cadd(apc, bpd);
        float2 y1 = cmul(w1, cadd(amc, sj));
        float2 y2 = cmul(w2, csub(apc, bpd));
        float2 y3 = cmul(w3, csub(amc, sj));
        int wb = q + 4 * s * p;
        dst[P(wb)]         = y0;
        dst[P(wb + s)]     = y1;
        dst[P(wb + 2 * s)] = y2;
        dst[P(wb + 3 * s)] = y3;
    }
}

__global__ __launch_bounds__(512) void stft_chain_kernel(
    const float* __restrict__ transfer,
    const float* __restrict__ gainp,
    float* __restrict__ io)
{
    __shared__ float2 bufs[2][FCHUNK][BUFSZ];   // ~139.3 KB ping-pong
    __shared__ float2 onys[FCHUNK];

    const int bd  = blockIdx.x;        // 0..255
    const int d   = bd & 63;
    const int tid = threadIdx.x;       // 0..511
    const int lf  = tid >> 6;          // frame within chunk (0..7) == wave id
    const int lt  = tid & 63;          // butterfly lane within that FFT
    const float g = gainp[0];
    const size_t base = (size_t)bd * TIME_N;
    const float PI  = 3.14159265358979323846f;
    const float PI2 = 6.2831853071795864769f;
    const float inv = 1.0f / 1024.0f;
    const float cd = __cosf(PI / 1024.0f);   // window step rotation
    const float sd = __sinf(PI / 1024.0f);

    // --- persistent per-thread state: 2 bins, 2 OLA tails ---
    const float T0 = transfer[(size_t)d * NBINS + tid];
    const float T1 = transfer[(size_t)d * NBINS + tid + 512];
    const float Tny = (tid == 0) ? transfer[(size_t)d * NBINS + HALFN] : 0.f;
    float2 C0  = make_float2(0.f, 0.f);
    float2 C1  = make_float2(0.f, 0.f);
    float2 Cny = make_float2(0.f, 0.f);
    float tail0 = 0.f, tail1 = 0.f;

    for (int ch = 0; ch < NCHUNK; ++ch) {
        // ---------- fused fwd stage 0: global load + window + butterfly ----
        {
            const int fr = ch * FCHUNK + lf;
            const int tb = fr * HALFN;
            float2* dst = &bufs[0][lf][0];
#pragma unroll
            for (int r = 0; r < 4; ++r) {
                const int i = lt + r * 64;
                // window values for samples 2i,2i+1 (+512,+1024,+1536 offsets)
                float s_, c_; __sincosf((PI / 512.0f) * (float)i, &s_, &c_);
                float cD = c_ * cd - s_ * sd;    // cos(A + pi/1024)
                float sD = s_ * cd + c_ * sd;    // sin(A + pi/1024)
                int t0 = tb + 2 * i;             // always < TIME_N
                int t1 = t0 + 512;               // always < TIME_N
                int t2 = t0 + 1024;
                int t3 = t0 + 1536;
                float2 a  = *reinterpret_cast<const float2*>(io + base + t0);
                float2 bv = *reinterpret_cast<const float2*>(io + base + t1);
                float2 cv = make_float2(0.f, 0.f), dv = make_float2(0.f, 0.f);
                if (t2 < TIME_N) cv = *reinterpret_cast<const float2*>(io + base + t2);
                if (t3 < TIME_N) dv = *reinterpret_cast<const float2*>(io + base + t3);
                a.x  *= 0.5f - 0.5f * c_;  a.y  *= 0.5f - 0.5f * cD;
                bv.x *= 0.5f + 0.5f * s_;  bv.y *= 0.5f + 0.5f * sD;
                cv.x *= 0.5f + 0.5f * c_;  cv.y *= 0.5f + 0.5f * cD;
                dv.x *= 0.5f - 0.5f * s_;  dv.y *= 0.5f - 0.5f * sD;
                // radix-4 butterfly, k=0 (s=1, n=1024, p=i, q=0), SGN=-1
                float ang = -PI2 * (float)i * (1.0f / 1024.0f);
                float sn, cs; __sincosf(ang, &sn, &cs);
                float2 w1 = make_float2(cs, sn);
                float2 w2 = cmul(w1, w1);
                float2 w3 = cmul(w1, w2);
                float2 apc = cadd(a, cv), amc = csub(a, cv);
                float2 bpd = cadd(bv, dv), bmd = csub(bv, dv);
                float2 sj = make_float2(bmd.y, -bmd.x);   // -j*(b-d)
                float2 y0 = cadd(apc, bpd);
                float2 y1 = cmul(w1, cadd(amc, sj));
                float2 y2 = cmul(w2, csub(apc, bpd));
                float2 y3 = cmul(w3, csub(amc, sj));
                int wb = 4 * i;
                dst[P(wb)]     = y0;
                dst[P(wb + 1)] = y1;
                dst[P(wb + 2)] = y2;
                dst[P(wb + 3)] = y3;
            }
        }
        __syncthreads();

        // ---------- fwd stages 1..4 (ping-pong) ----------
        {
            int cur = 0;
#pragma unroll
            for (int k = 1; k < 5; ++k) {
                fft_stage<-1>(&bufs[cur][lf][0], &bufs[cur ^ 1][lf][0], lt, k);
                __syncthreads();
                cur ^= 1;
            }
        }
        // forward result in bufs[0]

        // ---------- rfft post-process + per-bin scan: bufs[0] -> bufs[1] --
        {
            float sH, cH; __sincosf((PI / HALFN) * (float)tid, &sH, &cH);
            // bin tid:     e^{-i pi k/1024} = ( cH, -sH)
            // bin tid+512: e^{-i pi(k+512)/1024} = (-sH, -cH)
#pragma unroll 4
            for (int f = 0; f < FCHUNK; ++f) {
                float2 Zk = bufs[0][f][P(tid)];
                float2 Zn = bufs[0][f][P((HALFN - tid) & (HALFN - 1))];
                float2 Fe = make_float2(0.5f * (Zk.x + Zn.x), 0.5f * (Zk.y - Zn.y));
                float2 Fo = make_float2(0.5f * (Zk.y + Zn.y), -0.5f * (Zk.x - Zn.x));
                float2 X  = cmul(make_float2(cH, -sH), Fo);
                X.x += Fe.x; X.y += Fe.y;
                C0.x = (X.x + C0.x) * T0;
                C0.y = (X.y + C0.y) * T0;
                bufs[1][f][P(tid)] = C0;
                if (tid == 0) {
                    float Xny = Zk.x - Zk.y;            // from z[0]
                    Cny.x = (Xny + Cny.x) * Tny;
                    Cny.y = Cny.y * Tny;
                    onys[f] = Cny;
                }
                float2 Zk1 = bufs[0][f][P(tid + 512)];
                float2 Zn1 = bufs[0][f][P(512 - tid)];
                float2 Fe1 = make_float2(0.5f * (Zk1.x + Zn1.x), 0.5f * (Zk1.y - Zn1.y));
                float2 Fo1 = make_float2(0.5f * (Zk1.y + Zn1.y), -0.5f * (Zk1.x - Zn1.x));
                float2 X1  = cmul(make_float2(-sH, -cH), Fo1);
                X1.x += Fe1.x; X1.y += Fe1.y;
                C1.x = (X1.x + C1.x) * T1;
                C1.y = (X1.y + C1.y) * T1;
                bufs[1][f][P(tid + 512)] = C1;
            }
        }
        __syncthreads();

        // ---------- irfft pre-process: bufs[1] -> bufs[0] ----------
        {
            float sH, cH; __sincosf((PI / HALFN) * (float)tid, &sH, &cH);
            // m:     e^{+i pi m/1024} = ( cH,  sH)
            // m+512: e^{+i pi(m+512)/1024} = (-sH,  cH)
#pragma unroll 4
            for (int f = 0; f < FCHUNK; ++f) {
                float2 Om = bufs[1][f][P(tid)];
                float2 On = (tid == 0) ? onys[f] : bufs[1][f][P(HALFN - tid)];
                float2 Fe  = make_float2(0.5f * (Om.x + On.x), 0.5f * (Om.y - On.y));
                float2 num = make_float2(0.5f * (Om.x - On.x), 0.5f * (Om.y + On.y));
                float2 Fo  = cmul(make_float2(cH, sH), num);
                bufs[0][f][P(tid)] = make_float2(Fe.x - Fo.y, Fe.y + Fo.x);
                float2 Om1 = bufs[1][f][P(tid + 512)];
                float2 On1 = bufs[1][f][P(512 - tid)];
                float2 Fe1  = make_float2(0.5f * (Om1.x + On1.x), 0.5f * (Om1.y - On1.y));
                float2 num1 = make_float2(0.5f * (Om1.x - On1.x), 0.5f * (Om1.y + On1.y));
                float2 Fo1  = cmul(make_float2(-sH, cH), num1);
                bufs[0][f][P(tid + 512)] = make_float2(Fe1.x - Fo1.y, Fe1.y + Fo1.x);
            }
        }
        __syncthreads();

        // ---------- inverse FFTs: 5 stages from bufs[0] -> ends bufs[1] ---
        {
            int cur = 0;
#pragma unroll
            for (int k = 0; k < 5; ++k) {
                fft_stage<1>(&bufs[cur][lf][0], &bufs[cur ^ 1][lf][0], lt, k);
                __syncthreads();
                cur ^= 1;
            }
        }
        // inverse result in bufs[1]

        // ---------- unpack + OLA + gain + tanh (reads bufs[1] only) ------
        {
            float sH, cH; __sincosf((PI / HALFN) * (float)tid, &sH, &cH);
            float wU0 = 0.5f - 0.5f * cH;   // w(tid)
            float wU1 = 0.5f + 0.5f * sH;   // w(tid+512)
            float wT0 = 0.5f + 0.5f * cH;   // w(tid+1024)
            float wT1 = 0.5f - 0.5f * sH;   // w(tid+1536)
#pragma unroll 4
            for (int f = 0; f < FCHUNK; ++f) {
                int fr = ch * FCHUNK + f;
                float2 zA = bufs[1][f][P(tid >> 1)];
                float2 zB = bufs[1][f][P(256 + (tid >> 1))];
                float2 zC = bufs[1][f][P(512 + (tid >> 1))];
                float2 zD = bufs[1][f][P(768 + (tid >> 1))];
                float xs0 = (tid & 1) ? zA.y : zA.x;
                float xs1 = (tid & 1) ? zB.y : zB.x;
                float xh0 = (tid & 1) ? zC.y : zC.x;
                float xh1 = (tid & 1) ? zD.y : zD.x;
                float v0 = tail0 + xs0 * inv * wU0;
                float v1 = tail1 + xs1 * inv * wU1;
                io[base + (size_t)fr * HALFN + tid]       = tanhf(g * v0);
                io[base + (size_t)fr * HALFN + tid + 512] = tanhf(g * v1);
                tail0 = xh0 * inv * wT0;
                tail1 = xh1 * inv * wT1;
            }
        }
        // no trailing barrier: next chunk's stage 0 writes only bufs[0];
        // its end-of-stage barrier orders the bufs[1] ping-pong reuse.
    }
}

// ---------------------------------------------------------------------------
extern "C" void kernel_launch(void* const* d_in, const int* in_sizes, int n_in,
                              void* d_out, int out_size, void* d_ws, size_t ws_size,
                              hipStream_t stream) {
    const float* x        = (const float*)d_in[0];   // (4,64,65536)
    const float* transfer = (const float*)d_in[1];   // (64,1025)
    const float* mixer    = (const float*)d_in[2];   // (64,64)
    const float* gain     = (const float*)d_in[3];   // (1,)
    float* out = (float*)d_out;                      // (4,64,65536)

    dim3 g1(TIME_N / TT, 4);
    mix_kernel<<<g1, 256, 0, stream>>>(x, mixer, out);

    stft_chain_kernel<<<256, 512, 0, stream>>>(transfer, gain, out);
}

// Round 9
// 206.789 us; speedup vs baseline: 2.1307x; 2.1307x over previous
//
#include <hip/hip_runtime.h>
#include <math.h>

#define TIME_N 65536
#define HALFN  1024
#define NBINS  1025
#define NFRAMES 64
#define FCHUNK 8
#define NCHUNK (NFRAMES / FCHUNK)   // 8

// ---------------------------------------------------------------------------
// Kernel 1: channel mixing  out[b,d,t] = sum_c x[b,c,t] * M[c,d]
// ---------------------------------------------------------------------------
#define TT 128
__global__ __launch_bounds__(256) void mix_kernel(const float* __restrict__ x,
                                                  const float* __restrict__ M,
                                                  float* __restrict__ out) {
    __shared__ float Ml[64 * 64];
    __shared__ float xt[64][136];
    const int b   = blockIdx.y;
    const int t0  = blockIdx.x * TT;
    const int tid = threadIdx.x;

    for (int i = tid; i < 64 * 64; i += 256) Ml[i] = M[i];

    for (int r = 0; r < 8; ++r) {
        int fi = tid + r * 256;
        int c  = fi >> 5;
        int t4 = fi & 31;
        float4 v = *reinterpret_cast<const float4*>(
            x + (size_t)(b * 64 + c) * TIME_N + t0 + t4 * 4);
        *reinterpret_cast<float4*>(&xt[c][t4 * 4]) = v;
    }
    __syncthreads();

    const int dq = tid >> 5;
    const int tq = tid & 31;

    float acc[8][4];
#pragma unroll
    for (int i = 0; i < 8; ++i)
#pragma unroll
        for (int j = 0; j < 4; ++j) acc[i][j] = 0.f;

    for (int c = 0; c < 64; ++c) {
        float xv[4];
#pragma unroll
        for (int j = 0; j < 4; ++j) xv[j] = xt[c][tq + 32 * j];
#pragma unroll
        for (int i = 0; i < 8; ++i) {
            float mv = Ml[c * 64 + dq * 8 + i];
#pragma unroll
            for (int j = 0; j < 4; ++j) acc[i][j] += xv[j] * mv;
        }
    }

#pragma unroll
    for (int i = 0; i < 8; ++i) {
        int d = dq * 8 + i;
        size_t baseo = (size_t)(b * 64 + d) * TIME_N + t0;
#pragma unroll
        for (int j = 0; j < 4; ++j) out[baseo + tq + 32 * j] = acc[i][j];
    }
}

// ---------------------------------------------------------------------------
// Kernel 2: fused STFT -> per-bin frame recursion -> iSTFT -> OLA -> tanh.
// 256 blocks x 512 threads (128-VGPR budget regime). FCHUNK=8: wave f owns
// frame f -> FFT stages are wave-private (no __syncthreads; same-wave LDS
// ordering via lgkmcnt). Only 5 barriers per 8-frame chunk (40 total):
//   #1 post-fwd (scan reads all frames)   #2 post-scan (irfft-pre pairs)
//   #3 post-irfft-pre (waves gather Z')   #4 halves handoff (OLA)
//   #5 loop end (ping-pong buffer reuse)
// Chunk-crossing OLA tail: parity-double-buffered tailbuf.
// All loops unroll<=2 to stay spill-free (R8 lesson).
// ---------------------------------------------------------------------------
__device__ __forceinline__ int P(int i) { return i + (i >> 4); }   // pad-16
#define BUFSZ 1088   // P(1023) = 1086

__device__ __forceinline__ float2 cadd(float2 a, float2 b){return make_float2(a.x+b.x, a.y+b.y);}
__device__ __forceinline__ float2 csub(float2 a, float2 b){return make_float2(a.x-b.x, a.y-b.y);}
__device__ __forceinline__ float2 cmul(float2 a, float2 b){return make_float2(a.x*b.x - a.y*b.y, a.x*b.y + a.y*b.x);}

// Radix-4 self-sorting Stockham stage (ping-pong). lt in [0,64):
// butterflies i = lt + r*64, r = 0..3.  k = stage index. Wave-private.
template<int SGN>
__device__ __forceinline__ void fft_stage(const float2* __restrict__ src,
                                          float2* __restrict__ dst,
                                          int lt, int k) {
    const float PI2 = 6.2831853071795864769f;
    const int s = 1 << (2 * k);
    const int n = 1024 >> (2 * k);
#pragma unroll 2
    for (int r = 0; r < 4; ++r) {
        const int i = lt + r * 64;
        const int p = i >> (2 * k);
        const int q = i & (s - 1);
        float2 a  = src[P(i)];
        float2 bv = src[P(i + 256)];
        float2 cv = src[P(i + 512)];
        float2 dv = src[P(i + 768)];
        float ang = (float)SGN * PI2 * (float)p / (float)n;
        float sn, cs; __sincosf(ang, &sn, &cs);
        float2 w1 = make_float2(cs, sn);
        float2 w2 = cmul(w1, w1);
        float2 w3 = cmul(w1, w2);
        float2 apc = cadd(a, cv), amc = csub(a, cv);
        float2 bpd = cadd(bv, dv), bmd = csub(bv, dv);
        float2 sj = make_float2(-(float)SGN * bmd.y, (float)SGN * bmd.x);
        float2 y0 = cadd(apc, bpd);
        float2 y1 = cmul(w1, cadd(amc, sj));
        float2 y2 = cmul(w2, csub(apc, bpd));
        float2 y3 = cmul(w3, csub(amc, sj));
        int wb = q + 4 * s * p;
        dst[P(wb)]         = y0;
        dst[P(wb + s)]     = y1;
        dst[P(wb + 2 * s)] = y2;
        dst[P(wb + 3 * s)] = y3;
    }
}

__global__ __launch_bounds__(512) void stft_chain_kernel(
    const float* __restrict__ transfer,
    const float* __restrict__ gainp,
    float* __restrict__ io)
{
    __shared__ float2 bufs[2][FCHUNK][BUFSZ];   // 139.3 KB ping-pong
    __shared__ float2 tailbuf[2][512];          // 8 KB chunk-crossing OLA tail
    __shared__ float2 onys[FCHUNK];

    const int bd  = blockIdx.x;        // 0..255
    const int d   = bd & 63;
    const int tid = threadIdx.x;       // 0..511
    const int lf  = tid >> 6;          // frame within chunk (0..7) == wave id
    const int lt  = tid & 63;          // lane within that frame's FFT
    const float g = gainp[0];
    const size_t base = (size_t)bd * TIME_N;
    const float PI  = 3.14159265358979323846f;
    const float inv = 1.0f / 1024.0f;
    const float cd = __cosf(PI / 1024.0f);   // window step rotation
    const float sd = __sinf(PI / 1024.0f);

    // --- persistent per-thread state: 2 bins, Nyquist on tid 0 ---
    const float T0 = transfer[(size_t)d * NBINS + tid];
    const float T1 = transfer[(size_t)d * NBINS + tid + 512];
    const float Tny = (tid == 0) ? transfer[(size_t)d * NBINS + HALFN] : 0.f;
    float2 C0  = make_float2(0.f, 0.f);
    float2 C1  = make_float2(0.f, 0.f);
    float2 Cny = make_float2(0.f, 0.f);

    // zero-init OLA tail buffers (barriers #1..#4 of chunk 0 order this
    // before the first cross-wave read in phase B)
    tailbuf[0][tid] = make_float2(0.f, 0.f);
    tailbuf[1][tid] = make_float2(0.f, 0.f);

    for (int ch = 0; ch < NCHUNK; ++ch) {
        const int par = ch & 1;

        // ---- load + Hann window (wave-private; NO barrier) ----
        {
            const int fr = ch * FCHUNK + lf;
            const int tb = fr * HALFN;
            float2* dst = &bufs[0][lf][0];
#pragma unroll 2
            for (int j = 0; j < 8; ++j) {
                int u = lt + 64 * j;                  // 0..511
                int t = tb + 4 * u;
                float4 v = make_float4(0.f, 0.f, 0.f, 0.f);
                if (t < TIME_N)
                    v = *reinterpret_cast<const float4*>(io + base + t);
                float s0, c0; __sincosf((PI / 256.0f) * (float)u, &s0, &c0);
                float c1 = c0 * cd - s0 * sd, s1 = s0 * cd + c0 * sd;
                float c2 = c1 * cd - s1 * sd, s2 = s1 * cd + c1 * sd;
                float c3 = c2 * cd - s2 * sd;
                dst[P(2 * u)]     = make_float2(v.x * (0.5f - 0.5f * c0),
                                                v.y * (0.5f - 0.5f * c1));
                dst[P(2 * u + 1)] = make_float2(v.z * (0.5f - 0.5f * c2),
                                                v.w * (0.5f - 0.5f * c3));
            }
        }

        // ---- forward FFT: 5 wave-private stages (NO barriers) ----
#pragma unroll
        for (int k = 0; k < 5; ++k)
            fft_stage<-1>(&bufs[k & 1][lf][0], &bufs[(k & 1) ^ 1][lf][0], lt, k);
        // result in bufs[1]

        __syncthreads();   // #1: all frames' Z ready

        // ---- rfft post-process + per-bin scan: bufs[1] -> bufs[0] ----
        {
            float sH, cH; __sincosf((PI / HALFN) * (float)tid, &sH, &cH);
            // bin tid:     e^{-i pi k/1024} = ( cH, -sH)
            // bin tid+512: e^{-i pi(k+512)/1024} = (-sH, -cH)
#pragma unroll 2
            for (int f = 0; f < FCHUNK; ++f) {
                float2 Zk = bufs[1][f][P(tid)];
                float2 Zn = bufs[1][f][P((HALFN - tid) & (HALFN - 1))];
                float2 Fe = make_float2(0.5f * (Zk.x + Zn.x), 0.5f * (Zk.y - Zn.y));
                float2 Fo = make_float2(0.5f * (Zk.y + Zn.y), -0.5f * (Zk.x - Zn.x));
                float2 X  = cmul(make_float2(cH, -sH), Fo);
                X.x += Fe.x; X.y += Fe.y;
                C0.x = (X.x + C0.x) * T0;
                C0.y = (X.y + C0.y) * T0;
                bufs[0][f][P(tid)] = C0;
                if (tid == 0) {
                    float Xny = Zk.x - Zk.y;            // from z[0]
                    Cny.x = (Xny + Cny.x) * Tny;
                    Cny.y = Cny.y * Tny;
                    onys[f] = Cny;
                }
                float2 Zk1 = bufs[1][f][P(tid + 512)];
                float2 Zn1 = bufs[1][f][P(512 - tid)];
                float2 Fe1 = make_float2(0.5f * (Zk1.x + Zn1.x), 0.5f * (Zk1.y - Zn1.y));
                float2 Fo1 = make_float2(0.5f * (Zk1.y + Zn1.y), -0.5f * (Zk1.x - Zn1.x));
                float2 X1  = cmul(make_float2(-sH, -cH), Fo1);
                X1.x += Fe1.x; X1.y += Fe1.y;
                C1.x = (X1.x + C1.x) * T1;
                C1.y = (X1.y + C1.y) * T1;
                bufs[0][f][P(tid + 512)] = C1;
            }
        }
        __syncthreads();   // #2: all O ready

        // ---- irfft pre-process: bufs[0] -> bufs[1] ----
        {
            float sH, cH; __sincosf((PI / HALFN) * (float)tid, &sH, &cH);
            // m:     e^{+i pi m/1024} = ( cH,  sH)
            // m+512: e^{+i pi(m+512)/1024} = (-sH,  cH)
#pragma unroll 2
            for (int f = 0; f < FCHUNK; ++f) {
                float2 Om = bufs[0][f][P(tid)];
                float2 On = (tid == 0) ? onys[f] : bufs[0][f][P(HALFN - tid)];
                float2 Fe  = make_float2(0.5f * (Om.x + On.x), 0.5f * (Om.y - On.y));
                float2 num = make_float2(0.5f * (Om.x - On.x), 0.5f * (Om.y + On.y));
                float2 Fo  = cmul(make_float2(cH, sH), num);
                bufs[1][f][P(tid)] = make_float2(Fe.x - Fo.y, Fe.y + Fo.x);
                float2 Om1 = bufs[0][f][P(tid + 512)];
                float2 On1 = bufs[0][f][P(512 - tid)];
                float2 Fe1  = make_float2(0.5f * (Om1.x + On1.x), 0.5f * (Om1.y - On1.y));
                float2 num1 = make_float2(0.5f * (Om1.x - On1.x), 0.5f * (Om1.y + On1.y));
                float2 Fo1  = cmul(make_float2(-sH, cH), num1);
                bufs[1][f][P(tid + 512)] = make_float2(Fe1.x - Fo1.y, Fe1.y + Fo1.x);
            }
        }
        __syncthreads();   // #3: Z' ready for every frame

        // ---- inverse FFT: 5 wave-private stages (NO barriers) ----
#pragma unroll
        for (int k = 0; k < 5; ++k)
            fft_stage<1>(&bufs[(k & 1) ^ 1][lf][0], &bufs[k & 1][lf][0], lt, k);
        // result in bufs[0]

        // ---- phase A: windowed second half -> halves (wave-private write) --
        {
#pragma unroll 2
            for (int j = 8; j < 16; ++j) {
                int m = lt + 64 * j;                   // 512..1023
                float2 z = bufs[0][lf][P(m)];
                float s0, c0; __sincosf((PI / 512.0f) * (float)m, &s0, &c0);
                float c1 = c0 * cd - s0 * sd;
                float2 y = make_float2(z.x * inv * (0.5f - 0.5f * c0),
                                       z.y * inv * (0.5f - 0.5f * c1));
                if (lf == 7) tailbuf[par][m - 512] = y;          // -> next chunk
                else         bufs[1][lf][P(m - 512)] = y;        // -> wave lf+1
            }
        }
        __syncthreads();   // #4: halves handoff

        // ---- phase B: first half + prev second half, tanh, store ----
        {
            const int fr = ch * FCHUNK + lf;
            const int tb = fr * HALFN;
#pragma unroll 2
            for (int j = 0; j < 8; ++j) {
                int m = lt + 64 * j;                   // 0..511
                float2 z = bufs[0][lf][P(m)];
                float s0, c0; __sincosf((PI / 512.0f) * (float)m, &s0, &c0);
                float c1 = c0 * cd - s0 * sd;
                float y0 = z.x * inv * (0.5f - 0.5f * c0);
                float y1 = z.y * inv * (0.5f - 0.5f * c1);
                float2 prev = (lf == 0) ? tailbuf[par ^ 1][m]
                                        : bufs[1][lf - 1][P(m)];
                float2 o = make_float2(tanhf(g * (y0 + prev.x)),
                                       tanhf(g * (y1 + prev.y)));
                *reinterpret_cast<float2*>(io + base + tb + 2 * m) = o;
            }
        }
        __syncthreads();   // #5: protect ping-pong buffers before next chunk
    }
}

// ---------------------------------------------------------------------------
extern "C" void kernel_launch(void* const* d_in, const int* in_sizes, int n_in,
                              void* d_out, int out_size, void* d_ws, size_t ws_size,
                              hipStream_t stream) {
    const float* x        = (const float*)d_in[0];   // (4,64,65536)
    const float* transfer = (const float*)d_in[1];   // (64,1025)
    const float* mixer    = (const float*)d_in[2];   // (64,64)
    const float* gain     = (const float*)d_in[3];   // (1,)
    float* out = (float*)d_out;                      // (4,64,65536)

    dim3 g1(TIME_N / TT, 4);
    mix_kernel<<<g1, 256, 0, stream>>>(x, mixer, out);

    stft_chain_kernel<<<256, 512, 0, stream>>>(transfer, gain, out);
}

// Round 10
// 188.465 us; speedup vs baseline: 2.3379x; 1.0972x over previous
//
#include <hip/hip_runtime.h>
#include <math.h>

#define TIME_N 65536
#define HALFN  1024
#define NBINS  1025
#define NFRAMES 64
#define FCHUNK 8
#define NCHUNK (NFRAMES / FCHUNK)   // 8

// ---------------------------------------------------------------------------
// Kernel 1: channel mixing  out[b,d,t] = sum_c x[b,c,t] * M[c,d]
// ---------------------------------------------------------------------------
#define TT 128
__global__ __launch_bounds__(256) void mix_kernel(const float* __restrict__ x,
                                                  const float* __restrict__ M,
                                                  float* __restrict__ out) {
    __shared__ float Ml[64 * 64];
    __shared__ float xt[64][136];
    const int b   = blockIdx.y;
    const int t0  = blockIdx.x * TT;
    const int tid = threadIdx.x;

    for (int i = tid; i < 64 * 64; i += 256) Ml[i] = M[i];

    for (int r = 0; r < 8; ++r) {
        int fi = tid + r * 256;
        int c  = fi >> 5;
        int t4 = fi & 31;
        float4 v = *reinterpret_cast<const float4*>(
            x + (size_t)(b * 64 + c) * TIME_N + t0 + t4 * 4);
        *reinterpret_cast<float4*>(&xt[c][t4 * 4]) = v;
    }
    __syncthreads();

    const int dq = tid >> 5;
    const int tq = tid & 31;

    float acc[8][4];
#pragma unroll
    for (int i = 0; i < 8; ++i)
#pragma unroll
        for (int j = 0; j < 4; ++j) acc[i][j] = 0.f;

    for (int c = 0; c < 64; ++c) {
        float xv[4];
#pragma unroll
        for (int j = 0; j < 4; ++j) xv[j] = xt[c][tq + 32 * j];
#pragma unroll
        for (int i = 0; i < 8; ++i) {
            float mv = Ml[c * 64 + dq * 8 + i];
#pragma unroll
            for (int j = 0; j < 4; ++j) acc[i][j] += xv[j] * mv;
        }
    }

#pragma unroll
    for (int i = 0; i < 8; ++i) {
        int d = dq * 8 + i;
        size_t baseo = (size_t)(b * 64 + d) * TIME_N + t0;
#pragma unroll
        for (int j = 0; j < 4; ++j) out[baseo + tq + 32 * j] = acc[i][j];
    }
}

// ---------------------------------------------------------------------------
// Kernel 2: fused STFT -> per-bin frame recursion -> iSTFT -> OLA -> tanh.
// R9 structure (wave-private FFTs, 5 barriers per 8-frame chunk, spill-free
// 512-thread / 128-VGPR regime) + two VALU cuts:
//   * LDS twiddle table tw[768]: stage twiddle = tw[i & ~(s-1)], w2/w3 by
//     index doubling -> replaces per-butterfly __sincosf + 2 cmuls with LDS
//     pipe reads (broadcast in later stages).
//   * fast tanh via __expf + v_rcp (error ~1e-6 << 2e-2 threshold).
// ---------------------------------------------------------------------------
__device__ __forceinline__ int P(int i) { return i + (i >> 4); }   // pad-16
#define BUFSZ 1088   // P(1023) = 1086

__device__ __forceinline__ float2 cadd(float2 a, float2 b){return make_float2(a.x+b.x, a.y+b.y);}
__device__ __forceinline__ float2 csub(float2 a, float2 b){return make_float2(a.x-b.x, a.y-b.y);}
__device__ __forceinline__ float2 cmul(float2 a, float2 b){return make_float2(a.x*b.x - a.y*b.y, a.x*b.y + a.y*b.x);}

__device__ __forceinline__ float ftanh(float x) {
    float ax = fabsf(x);
    float e  = __expf(-2.0f * ax);
    float t  = (1.0f - e) * __builtin_amdgcn_rcpf(1.0f + e);
    return copysignf(t, x);
}

// Radix-4 self-sorting Stockham stage (ping-pong, wave-private).
// lt in [0,64): butterflies i = lt + r*64.  Twiddles from LDS table.
template<int SGN>
__device__ __forceinline__ void fft_stage(const float2* __restrict__ src,
                                          float2* __restrict__ dst,
                                          const float2* __restrict__ tw,
                                          int lt, int k) {
    const int s = 1 << (2 * k);
#pragma unroll 2
    for (int r = 0; r < 4; ++r) {
        const int i = lt + r * 64;
        const int q = i & (s - 1);
        const int j = i & ~(s - 1);          // = (i>>2k)<<2k
        float2 a  = src[P(i)];
        float2 bv = src[P(i + 256)];
        float2 cv = src[P(i + 512)];
        float2 dv = src[P(i + 768)];
        float2 w1 = tw[j];
        float2 w2 = tw[2 * j];
        float2 w3 = tw[3 * j];
        if (SGN > 0) { w1.y = -w1.y; w2.y = -w2.y; w3.y = -w3.y; }
        float2 apc = cadd(a, cv), amc = csub(a, cv);
        float2 bpd = cadd(bv, dv), bmd = csub(bv, dv);
        float2 sj = make_float2(-(float)SGN * bmd.y, (float)SGN * bmd.x);
        float2 y0 = cadd(apc, bpd);
        float2 y1 = cmul(w1, cadd(amc, sj));
        float2 y2 = cmul(w2, csub(apc, bpd));
        float2 y3 = cmul(w3, csub(amc, sj));
        int wb = q + 4 * (i - q);            // q + 4*s*p
        dst[P(wb)]         = y0;
        dst[P(wb + s)]     = y1;
        dst[P(wb + 2 * s)] = y2;
        dst[P(wb + 3 * s)] = y3;
    }
}

__global__ __launch_bounds__(512) void stft_chain_kernel(
    const float* __restrict__ transfer,
    const float* __restrict__ gainp,
    float* __restrict__ io)
{
    __shared__ float2 bufs[2][FCHUNK][BUFSZ];   // 139.3 KB ping-pong
    __shared__ float2 tailbuf[2][512];          // 8 KB chunk-crossing OLA tail
    __shared__ float2 twl[768];                 // 6 KB twiddle table e^{-2pi i j/1024}
    __shared__ float2 onys[FCHUNK];

    const int bd  = blockIdx.x;        // 0..255
    const int d   = bd & 63;
    const int tid = threadIdx.x;       // 0..511
    const int lf  = tid >> 6;          // frame within chunk (0..7) == wave id
    const int lt  = tid & 63;          // lane within that frame's FFT
    const float g = gainp[0];
    const size_t base = (size_t)bd * TIME_N;
    const float PI  = 3.14159265358979323846f;
    const float PI2 = 6.2831853071795864769f;
    const float inv = 1.0f / 1024.0f;
    const float cd = __cosf(PI / 1024.0f);   // window step rotation
    const float sd = __sinf(PI / 1024.0f);

    // --- persistent per-thread state: 2 bins, Nyquist on tid 0 ---
    const float T0 = transfer[(size_t)d * NBINS + tid];
    const float T1 = transfer[(size_t)d * NBINS + tid + 512];
    const float Tny = (tid == 0) ? transfer[(size_t)d * NBINS + HALFN] : 0.f;
    float2 C0  = make_float2(0.f, 0.f);
    float2 C1  = make_float2(0.f, 0.f);
    float2 Cny = make_float2(0.f, 0.f);

    // one-time LDS init: OLA tails + twiddle table
    tailbuf[0][tid] = make_float2(0.f, 0.f);
    tailbuf[1][tid] = make_float2(0.f, 0.f);
    for (int j = tid; j < 768; j += 512) {
        float s_, c_; __sincosf(-(PI2 / 1024.0f) * (float)j, &s_, &c_);
        twl[j] = make_float2(c_, s_);
    }
    __syncthreads();

    for (int ch = 0; ch < NCHUNK; ++ch) {
        const int par = ch & 1;

        // ---- load + Hann window (wave-private; NO barrier) ----
        {
            const int fr = ch * FCHUNK + lf;
            const int tb = fr * HALFN;
            float2* dst = &bufs[0][lf][0];
#pragma unroll 2
            for (int j = 0; j < 8; ++j) {
                int u = lt + 64 * j;                  // 0..511
                int t = tb + 4 * u;
                float4 v = make_float4(0.f, 0.f, 0.f, 0.f);
                if (t < TIME_N)
                    v = *reinterpret_cast<const float4*>(io + base + t);
                float s0, c0; __sincosf((PI / 256.0f) * (float)u, &s0, &c0);
                float c1 = c0 * cd - s0 * sd, s1 = s0 * cd + c0 * sd;
                float c2 = c1 * cd - s1 * sd, s2 = s1 * cd + c1 * sd;
                float c3 = c2 * cd - s2 * sd;
                dst[P(2 * u)]     = make_float2(v.x * (0.5f - 0.5f * c0),
                                                v.y * (0.5f - 0.5f * c1));
                dst[P(2 * u + 1)] = make_float2(v.z * (0.5f - 0.5f * c2),
                                                v.w * (0.5f - 0.5f * c3));
            }
        }

        // ---- forward FFT: 5 wave-private stages (NO barriers) ----
#pragma unroll
        for (int k = 0; k < 5; ++k)
            fft_stage<-1>(&bufs[k & 1][lf][0], &bufs[(k & 1) ^ 1][lf][0], twl, lt, k);
        // result in bufs[1]

        __syncthreads();   // #1: all frames' Z ready

        // ---- rfft post-process + per-bin scan: bufs[1] -> bufs[0] ----
        {
            float sH, cH; __sincosf((PI / HALFN) * (float)tid, &sH, &cH);
            // bin tid:     e^{-i pi k/1024} = ( cH, -sH)
            // bin tid+512: e^{-i pi(k+512)/1024} = (-sH, -cH)
#pragma unroll 2
            for (int f = 0; f < FCHUNK; ++f) {
                float2 Zk = bufs[1][f][P(tid)];
                float2 Zn = bufs[1][f][P((HALFN - tid) & (HALFN - 1))];
                float2 Fe = make_float2(0.5f * (Zk.x + Zn.x), 0.5f * (Zk.y - Zn.y));
                float2 Fo = make_float2(0.5f * (Zk.y + Zn.y), -0.5f * (Zk.x - Zn.x));
                float2 X  = cmul(make_float2(cH, -sH), Fo);
                X.x += Fe.x; X.y += Fe.y;
                C0.x = (X.x + C0.x) * T0;
                C0.y = (X.y + C0.y) * T0;
                bufs[0][f][P(tid)] = C0;
                if (tid == 0) {
                    float Xny = Zk.x - Zk.y;            // from z[0]
                    Cny.x = (Xny + Cny.x) * Tny;
                    Cny.y = Cny.y * Tny;
                    onys[f] = Cny;
                }
                float2 Zk1 = bufs[1][f][P(tid + 512)];
                float2 Zn1 = bufs[1][f][P(512 - tid)];
                float2 Fe1 = make_float2(0.5f * (Zk1.x + Zn1.x), 0.5f * (Zk1.y - Zn1.y));
                float2 Fo1 = make_float2(0.5f * (Zk1.y + Zn1.y), -0.5f * (Zk1.x - Zn1.x));
                float2 X1  = cmul(make_float2(-sH, -cH), Fo1);
                X1.x += Fe1.x; X1.y += Fe1.y;
                C1.x = (X1.x + C1.x) * T1;
                C1.y = (X1.y + C1.y) * T1;
                bufs[0][f][P(tid + 512)] = C1;
            }
        }
        __syncthreads();   // #2: all O ready

        // ---- irfft pre-process: bufs[0] -> bufs[1] ----
        {
            float sH, cH; __sincosf((PI / HALFN) * (float)tid, &sH, &cH);
            // m:     e^{+i pi m/1024} = ( cH,  sH)
            // m+512: e^{+i pi(m+512)/1024} = (-sH,  cH)
#pragma unroll 2
            for (int f = 0; f < FCHUNK; ++f) {
                float2 Om = bufs[0][f][P(tid)];
                float2 On = (tid == 0) ? onys[f] : bufs[0][f][P(HALFN - tid)];
                float2 Fe  = make_float2(0.5f * (Om.x + On.x), 0.5f * (Om.y - On.y));
                float2 num = make_float2(0.5f * (Om.x - On.x), 0.5f * (Om.y + On.y));
                float2 Fo  = cmul(make_float2(cH, sH), num);
                bufs[1][f][P(tid)] = make_float2(Fe.x - Fo.y, Fe.y + Fo.x);
                float2 Om1 = bufs[0][f][P(tid + 512)];
                float2 On1 = bufs[0][f][P(512 - tid)];
                float2 Fe1  = make_float2(0.5f * (Om1.x + On1.x), 0.5f * (Om1.y - On1.y));
                float2 num1 = make_float2(0.5f * (Om1.x - On1.x), 0.5f * (Om1.y + On1.y));
                float2 Fo1  = cmul(make_float2(-sH, cH), num1);
                bufs[1][f][P(tid + 512)] = make_float2(Fe1.x - Fo1.y, Fe1.y + Fo1.x);
            }
        }
        __syncthreads();   // #3: Z' ready for every frame

        // ---- inverse FFT: 5 wave-private stages (NO barriers) ----
#pragma unroll
        for (int k = 0; k < 5; ++k)
            fft_stage<1>(&bufs[(k & 1) ^ 1][lf][0], &bufs[k & 1][lf][0], twl, lt, k);
        // result in bufs[0]

        // ---- phase A: windowed second half -> halves (wave-private write) --
        {
#pragma unroll 2
            for (int j = 8; j < 16; ++j) {
                int m = lt + 64 * j;                   // 512..1023
                float2 z = bufs[0][lf][P(m)];
                float s0, c0; __sincosf((PI / 512.0f) * (float)m, &s0, &c0);
                float c1 = c0 * cd - s0 * sd;
                float2 y = make_float2(z.x * inv * (0.5f - 0.5f * c0),
                                       z.y * inv * (0.5f - 0.5f * c1));
                if (lf == 7) tailbuf[par][m - 512] = y;          // -> next chunk
                else         bufs[1][lf][P(m - 512)] = y;        // -> wave lf+1
            }
        }
        __syncthreads();   // #4: halves handoff

        // ---- phase B: first half + prev second half, tanh, store ----
        {
            const int fr = ch * FCHUNK + lf;
            const int tb = fr * HALFN;
#pragma unroll 2
            for (int j = 0; j < 8; ++j) {
                int m = lt + 64 * j;                   // 0..511
                float2 z = bufs[0][lf][P(m)];
                float s0, c0; __sincosf((PI / 512.0f) * (float)m, &s0, &c0);
                float c1 = c0 * cd - s0 * sd;
                float y0 = z.x * inv * (0.5f - 0.5f * c0);
                float y1 = z.y * inv * (0.5f - 0.5f * c1);
                float2 prev = (lf == 0) ? tailbuf[par ^ 1][m]
                                        : bufs[1][lf - 1][P(m)];
                float2 o = make_float2(ftanh(g * (y0 + prev.x)),
                                       ftanh(g * (y1 + prev.y)));
                *reinterpret_cast<float2*>(io + base + tb + 2 * m) = o;
            }
        }
        __syncthreads();   // #5: protect ping-pong buffers before next chunk
    }
}

// ---------------------------------------------------------------------------
extern "C" void kernel_launch(void* const* d_in, const int* in_sizes, int n_in,
                              void* d_out, int out_size, void* d_ws, size_t ws_size,
                              hipStream_t stream) {
    const float* x        = (const float*)d_in[0];   // (4,64,65536)
    const float* transfer = (const float*)d_in[1];   // (64,1025)
    const float* mixer    = (const float*)d_in[2];   // (64,64)
    const float* gain     = (const float*)d_in[3];   // (1,)
    float* out = (float*)d_out;                      // (4,64,65536)

    dim3 g1(TIME_N / TT, 4);
    mix_kernel<<<g1, 256, 0, stream>>>(x, mixer, out);

    stft_chain_kernel<<<256, 512, 0, stream>>>(transfer, gain, out);
}

// Round 11
// 172.374 us; speedup vs baseline: 2.5561x; 1.0934x over previous
//
#include <hip/hip_runtime.h>
#include <math.h>

#define TIME_N 65536
#define HALFN  1024
#define NBINS  1025
#define NFRAMES 64
#define FCHUNK 8
#define NCHUNK (NFRAMES / FCHUNK)   // 8

// ---------------------------------------------------------------------------
// Kernel 1: channel mixing  out[b,d,t] = sum_c x[b,c,t] * M[c,d]
// ---------------------------------------------------------------------------
#define TT 128
__global__ __launch_bounds__(256) void mix_kernel(const float* __restrict__ x,
                                                  const float* __restrict__ M,
                                                  float* __restrict__ out) {
    __shared__ float Ml[64 * 64];
    __shared__ float xt[64][136];
    const int b   = blockIdx.y;
    const int t0  = blockIdx.x * TT;
    const int tid = threadIdx.x;

    for (int i = tid; i < 64 * 64; i += 256) Ml[i] = M[i];

    for (int r = 0; r < 8; ++r) {
        int fi = tid + r * 256;
        int c  = fi >> 5;
        int t4 = fi & 31;
        float4 v = *reinterpret_cast<const float4*>(
            x + (size_t)(b * 64 + c) * TIME_N + t0 + t4 * 4);
        *reinterpret_cast<float4*>(&xt[c][t4 * 4]) = v;
    }
    __syncthreads();

    const int dq = tid >> 5;
    const int tq = tid & 31;

    float acc[8][4];
#pragma unroll
    for (int i = 0; i < 8; ++i)
#pragma unroll
        for (int j = 0; j < 4; ++j) acc[i][j] = 0.f;

    for (int c = 0; c < 64; ++c) {
        float xv[4];
#pragma unroll
        for (int j = 0; j < 4; ++j) xv[j] = xt[c][tq + 32 * j];
#pragma unroll
        for (int i = 0; i < 8; ++i) {
            float mv = Ml[c * 64 + dq * 8 + i];
#pragma unroll
            for (int j = 0; j < 4; ++j) acc[i][j] += xv[j] * mv;
        }
    }

#pragma unroll
    for (int i = 0; i < 8; ++i) {
        int d = dq * 8 + i;
        size_t baseo = (size_t)(b * 64 + d) * TIME_N + t0;
#pragma unroll
        for (int j = 0; j < 4; ++j) out[baseo + tq + 32 * j] = acc[i][j];
    }
}

// ---------------------------------------------------------------------------
// Kernel 2: fused STFT -> per-bin frame recursion -> iSTFT -> OLA -> tanh.
// R10 base (wave-private FFTs, LDS twiddles, fast tanh, 512 thr / spill-free)
// + conjugate-pair fusion: thread tid owns bins (tid, 1024-tid) so
// rfft-post + scan + irfft-pre collapse into ONE in-place phase (thread-
// exclusive slot pairs -> race-free), phase A eliminated (phase B reads raw
// neighbor half and applies the complementary window 1-w), window values
// from a 4KB LDS table. 4 barriers per 8-frame chunk (32 total).
// ---------------------------------------------------------------------------
__device__ __forceinline__ int P(int i) { return i + (i >> 4); }   // pad-16
#define BUFSZ 1088   // P(1023) = 1086

__device__ __forceinline__ float2 cadd(float2 a, float2 b){return make_float2(a.x+b.x, a.y+b.y);}
__device__ __forceinline__ float2 csub(float2 a, float2 b){return make_float2(a.x-b.x, a.y-b.y);}
__device__ __forceinline__ float2 cmul(float2 a, float2 b){return make_float2(a.x*b.x - a.y*b.y, a.x*b.y + a.y*b.x);}

__device__ __forceinline__ float ftanh(float x) {
    float ax = fabsf(x);
    float e  = __expf(-2.0f * ax);
    float t  = (1.0f - e) * __builtin_amdgcn_rcpf(1.0f + e);
    return copysignf(t, x);
}

// Radix-4 self-sorting Stockham stage (ping-pong, wave-private).
// lt in [0,64): butterflies i = lt + r*64 (i < 256).  Twiddles from LDS.
template<int SGN>
__device__ __forceinline__ void fft_stage(const float2* __restrict__ src,
                                          float2* __restrict__ dst,
                                          const float2* __restrict__ tw,
                                          int lt, int k) {
    const int s = 1 << (2 * k);
#pragma unroll 2
    for (int r = 0; r < 4; ++r) {
        const int i = lt + r * 64;
        const int q = i & (s - 1);
        const int j = i & ~(s - 1);
        float2 a  = src[P(i)];
        float2 bv = src[P(i + 256)];
        float2 cv = src[P(i + 512)];
        float2 dv = src[P(i + 768)];
        float2 w1 = tw[j];
        float2 w2 = tw[2 * j];
        float2 w3 = tw[3 * j];
        if (SGN > 0) { w1.y = -w1.y; w2.y = -w2.y; w3.y = -w3.y; }
        float2 apc = cadd(a, cv), amc = csub(a, cv);
        float2 bpd = cadd(bv, dv), bmd = csub(bv, dv);
        float2 sj = make_float2(-(float)SGN * bmd.y, (float)SGN * bmd.x);
        float2 y0 = cadd(apc, bpd);
        float2 y1 = cmul(w1, cadd(amc, sj));
        float2 y2 = cmul(w2, csub(apc, bpd));
        float2 y3 = cmul(w3, csub(amc, sj));
        int wb = q + 4 * (i - q);
        dst[P(wb)]         = y0;
        dst[P(wb + s)]     = y1;
        dst[P(wb + 2 * s)] = y2;
        dst[P(wb + 3 * s)] = y3;
    }
}

__global__ __launch_bounds__(512) void stft_chain_kernel(
    const float* __restrict__ transfer,
    const float* __restrict__ gainp,
    float* __restrict__ io)
{
    __shared__ float2 bufs[2][FCHUNK][BUFSZ];   // 139.3 KB ping-pong
    __shared__ float2 tailbuf[2][512];          // 8 KB raw chunk-crossing tail
    __shared__ float2 twl[768];                 // 6 KB twiddles e^{-2pi i j/1024}
    __shared__ float2 win2[512];                // 4 KB (win(2m), win(2m+1))

    const int bd  = blockIdx.x;        // 0..255
    const int d   = bd & 63;
    const int tid = threadIdx.x;       // 0..511
    const int lf  = tid >> 6;          // frame within chunk (0..7) == wave id
    const int lt  = tid & 63;          // lane within that frame's FFT
    const float g = gainp[0];
    const size_t base = (size_t)bd * TIME_N;
    const float PI  = 3.14159265358979323846f;
    const float PI2 = 6.2831853071795864769f;
    const float inv = 1.0f / 1024.0f;

    // --- persistent per-thread state: bin pair (tid, 1024-tid) + 512 on t0 ---
    const int kb = (tid == 0) ? 1024 : 1024 - tid;
    const float T0 = transfer[(size_t)d * NBINS + tid];
    const float T1 = transfer[(size_t)d * NBINS + kb];
    const float T5 = (tid == 0) ? transfer[(size_t)d * NBINS + 512] : 0.f;
    float2 C0 = make_float2(0.f, 0.f);
    float2 C1 = make_float2(0.f, 0.f);
    float2 C5 = make_float2(0.f, 0.f);
    float sHt, cHt; __sincosf((PI / HALFN) * (float)tid, &sHt, &cHt);

    // one-time LDS init
    tailbuf[0][tid] = make_float2(0.f, 0.f);
    tailbuf[1][tid] = make_float2(0.f, 0.f);
    for (int j = tid; j < 768; j += 512) {
        float s_, c_; __sincosf(-(PI2 / 1024.0f) * (float)j, &s_, &c_);
        twl[j] = make_float2(c_, s_);
    }
    {
        const float cd = __cosf(PI / 1024.0f);
        const float sd = __sinf(PI / 1024.0f);
        float s0, c0; __sincosf((PI / 512.0f) * (float)tid, &s0, &c0);
        float c1 = c0 * cd - s0 * sd;
        win2[tid] = make_float2(0.5f - 0.5f * c0, 0.5f - 0.5f * c1);
    }
    __syncthreads();

    for (int ch = 0; ch < NCHUNK; ++ch) {
        const int par = ch & 1;

        // ---- load + window (LDS table) -> bufs[0][lf]  (wave-private) ----
        {
            const int tb = (ch * FCHUNK + lf) * HALFN;
            float2* dst = &bufs[0][lf][0];
#pragma unroll
            for (int j = 0; j < 8; ++j) {
                int u = lt + 64 * j;                  // 0..511
                int t = tb + 4 * u;
                float4 v = make_float4(0.f, 0.f, 0.f, 0.f);
                if (t < TIME_N)
                    v = *reinterpret_cast<const float4*>(io + base + t);
                int m2 = (2 * u) & 511;
                float2 wa = win2[m2];
                float2 wb = win2[m2 + 1];
                if (j >= 4) {   // samples >= 1024: win = 1 - win(n-1024)
                    wa.x = 1.f - wa.x; wa.y = 1.f - wa.y;
                    wb.x = 1.f - wb.x; wb.y = 1.f - wb.y;
                }
                dst[P(2 * u)]     = make_float2(v.x * wa.x, v.y * wa.y);
                dst[P(2 * u + 1)] = make_float2(v.z * wb.x, v.w * wb.y);
            }
        }

        // ---- forward FFT: 5 wave-private stages (NO barriers) ----
#pragma unroll
        for (int k = 0; k < 5; ++k)
            fft_stage<-1>(&bufs[k & 1][lf][0], &bufs[(k & 1) ^ 1][lf][0], twl, lt, k);
        // result in bufs[1]

        __syncthreads();   // #1: all frames' Z ready

        // ---- FUSED rfft-post + scan + irfft-pre, in-place on bufs[1] ----
        // thread owns slots {tid, 1024-tid} (t0: {0,512}); prefetch next frame
        {
            float2 Zk = bufs[1][0][P(tid)];
            float2 Zn = bufs[1][0][P((HALFN - tid) & (HALFN - 1))];
#pragma unroll 2
            for (int f = 0; f < FCHUNK; ++f) {
                float2 Zk_n, Zn_n;
                if (f < FCHUNK - 1) {
                    Zk_n = bufs[1][f + 1][P(tid)];
                    Zn_n = bufs[1][f + 1][P((HALFN - tid) & (HALFN - 1))];
                }
                // rfft post-process (shared between conjugate pair)
                float2 Fe = make_float2(0.5f * (Zk.x + Zn.x), 0.5f * (Zk.y - Zn.y));
                float2 Fo = make_float2(0.5f * (Zk.y + Zn.y), -0.5f * (Zk.x - Zn.x));
                float2 U  = cmul(make_float2(cHt, -sHt), Fo);   // e^{-i pi k/1024}*Fo
                // X_k = Fe + U ; X_{1024-k} = conj(Fe - U)
                C0.x = (Fe.x + U.x + C0.x) * T0;
                C0.y = (Fe.y + U.y + C0.y) * T0;
                C1.x = (Fe.x - U.x + C1.x) * T1;
                C1.y = (U.y - Fe.y + C1.y) * T1;
                // irfft pre-process (pair shares Fe2/num/Fo2)
                float2 Fe2 = make_float2(0.5f * (C0.x + C1.x), 0.5f * (C0.y - C1.y));
                float2 num = make_float2(0.5f * (C0.x - C1.x), 0.5f * (C0.y + C1.y));
                float2 Fo2 = cmul(make_float2(cHt, sHt), num);  // e^{+i pi m/1024}*num
                bufs[1][f][P(tid)] = make_float2(Fe2.x - Fo2.y, Fe2.y + Fo2.x);
                if (tid != 0) {
                    bufs[1][f][P(HALFN - tid)] =
                        make_float2(Fe2.x + Fo2.y, Fo2.x - Fe2.y);
                } else {
                    // bin 512 (self-paired): X = conj(Z[512]); Z' = conj(O)
                    float2 Z5 = bufs[1][f][P(512)];
                    C5.x = ( Z5.x + C5.x) * T5;
                    C5.y = (-Z5.y + C5.y) * T5;
                    bufs[1][f][P(512)] = make_float2(C5.x, -C5.y);
                }
                Zk = Zk_n; Zn = Zn_n;
            }
        }
        __syncthreads();   // #2: all Z' ready

        // ---- inverse FFT: 5 wave-private stages (NO barriers) ----
#pragma unroll
        for (int k = 0; k < 5; ++k)
            fft_stage<1>(&bufs[(k & 1) ^ 1][lf][0], &bufs[k & 1][lf][0], twl, lt, k);
        // result in bufs[0]

        // ---- wave 7: stash raw second half for next chunk ----
        if (lf == 7) {
#pragma unroll 2
            for (int j = 0; j < 8; ++j) {
                int m = lt + 64 * j;                   // 0..511
                tailbuf[par][m] = bufs[0][7][P(m + 512)];
            }
        }
        __syncthreads();   // #3: inverse results + tail ready

        // ---- phase B: OLA (own first half + prev raw second half w/ 1-w),
        //      gain + tanh, store ----
        {
            const int tb = (ch * FCHUNK + lf) * HALFN;
#pragma unroll 2
            for (int j = 0; j < 8; ++j) {
                int m = lt + 64 * j;                   // 0..511
                float2 z  = bufs[0][lf][P(m)];
                float2 zp = (lf == 0) ? tailbuf[par ^ 1][m]
                                      : bufs[0][lf - 1][P(m + 512)];
                float2 wf = win2[m];
                float y0 = inv * (z.x * wf.x + zp.x * (1.f - wf.x));
                float y1 = inv * (z.y * wf.y + zp.y * (1.f - wf.y));
                float2 o = make_float2(ftanh(g * y0), ftanh(g * y1));
                *reinterpret_cast<float2*>(io + base + tb + 2 * m) = o;
            }
        }
        __syncthreads();   // #4: protect bufs before next chunk's overwrite
    }
}

// ---------------------------------------------------------------------------
extern "C" void kernel_launch(void* const* d_in, const int* in_sizes, int n_in,
                              void* d_out, int out_size, void* d_ws, size_t ws_size,
                              hipStream_t stream) {
    const float* x        = (const float*)d_in[0];   // (4,64,65536)
    const float* transfer = (const float*)d_in[1];   // (64,1025)
    const float* mixer    = (const float*)d_in[2];   // (64,64)
    const float* gain     = (const float*)d_in[3];   // (1,)
    float* out = (float*)d_out;                      // (4,64,65536)

    dim3 g1(TIME_N / TT, 4);
    mix_kernel<<<g1, 256, 0, stream>>>(x, mixer, out);

    stft_chain_kernel<<<256, 512, 0, stream>>>(transfer, gain, out);
}

// Round 12
// 136.788 us; speedup vs baseline: 3.2211x; 1.2602x over previous
//
#include <hip/hip_runtime.h>
#include <math.h>

#define TIME_N 65536
#define HALFN  1024
#define NBINS  1025
#define NFRAMES 64
#define FCHUNK 8
#define NCHUNK (NFRAMES / FCHUNK)   // 8

// ---------------------------------------------------------------------------
// Kernel 1: channel mixing  out[b,d,t] = sum_c x[b,c,t] * M[c,d]
// ---------------------------------------------------------------------------
#define TT 128
__global__ __launch_bounds__(256) void mix_kernel(const float* __restrict__ x,
                                                  const float* __restrict__ M,
                                                  float* __restrict__ out) {
    __shared__ float Ml[64 * 64];
    __shared__ float xt[64][136];
    const int b   = blockIdx.y;
    const int t0  = blockIdx.x * TT;
    const int tid = threadIdx.x;

    for (int i = tid; i < 64 * 64; i += 256) Ml[i] = M[i];

    for (int r = 0; r < 8; ++r) {
        int fi = tid + r * 256;
        int c  = fi >> 5;
        int t4 = fi & 31;
        float4 v = *reinterpret_cast<const float4*>(
            x + (size_t)(b * 64 + c) * TIME_N + t0 + t4 * 4);
        *reinterpret_cast<float4*>(&xt[c][t4 * 4]) = v;
    }
    __syncthreads();

    const int dq = tid >> 5;
    const int tq = tid & 31;

    float acc[8][4];
#pragma unroll
    for (int i = 0; i < 8; ++i)
#pragma unroll
        for (int j = 0; j < 4; ++j) acc[i][j] = 0.f;

    for (int c = 0; c < 64; ++c) {
        float xv[4];
#pragma unroll
        for (int j = 0; j < 4; ++j) xv[j] = xt[c][tq + 32 * j];
#pragma unroll
        for (int i = 0; i < 8; ++i) {
            float mv = Ml[c * 64 + dq * 8 + i];
#pragma unroll
            for (int j = 0; j < 4; ++j) acc[i][j] += xv[j] * mv;
        }
    }

#pragma unroll
    for (int i = 0; i < 8; ++i) {
        int d = dq * 8 + i;
        size_t baseo = (size_t)(b * 64 + d) * TIME_N + t0;
#pragma unroll
        for (int j = 0; j < 4; ++j) out[baseo + tq + 32 * j] = acc[i][j];
    }
}

// ---------------------------------------------------------------------------
// Kernel 2: fused STFT -> per-bin frame recursion -> iSTFT -> OLA -> tanh.
// R11 structure (wave-private frames, fused conj-pair scan, 4 barriers/chunk)
// with the FFT rebuilt as 1024 = 16*16*4 register-resident radix-16 Stockham:
//   stage A (s=1,R=16): global load + Hann window fused; DFT16 in regs
//   stage B (s=16,R=16): LDS->LDS; DFT16 in regs
//   stage C (s=256,R=4): twiddle-free, in-place
// External twiddle w^j folded as w^i*(w4)^m (5 cmuls from one twl[64] read);
// DFT16 internal twiddles are inline constants. ~2x fewer LDS ops/FFT.
// ---------------------------------------------------------------------------
__device__ __forceinline__ int P(int i) { return i + (i >> 4); }   // pad-16
#define BUFSZ 1088   // P(1023) = 1086

__device__ __forceinline__ float2 cadd(float2 a, float2 b){return make_float2(a.x+b.x, a.y+b.y);}
__device__ __forceinline__ float2 csub(float2 a, float2 b){return make_float2(a.x-b.x, a.y-b.y);}
__device__ __forceinline__ float2 cmul(float2 a, float2 b){return make_float2(a.x*b.x - a.y*b.y, a.x*b.y + a.y*b.x);}

__device__ __forceinline__ float ftanh(float x) {
    float ax = fabsf(x);
    float e  = __expf(-2.0f * ax);
    float t  = (1.0f - e) * __builtin_amdgcn_rcpf(1.0f + e);
    return copysignf(t, x);
}

// DFT4 (no twiddles): X_m with kernel e^{SGN*2pi i mk/4}
template<int SGN>
__device__ __forceinline__ void dft4(float2 x0, float2 x1, float2 x2, float2 x3,
                                     float2& y0, float2& y1, float2& y2, float2& y3) {
    float2 apc = cadd(x0, x2), amc = csub(x0, x2);
    float2 bpd = cadd(x1, x3), bmd = csub(x1, x3);
    float2 sj  = make_float2(-(float)SGN * bmd.y, (float)SGN * bmd.x);  // SGN*j*bmd
    y0 = cadd(apc, bpd);
    y1 = cadd(amc, sj);
    y2 = csub(apc, bpd);
    y3 = csub(amc, sj);
}

// z[j] = DFT16(x)[j] * w^j  (kernel e^{SGN*2pi i jk/16}; w = ext twiddle base)
template<int SGN>
__device__ __forceinline__ void dft16_tw(const float2 (&x)[16], float2 w, float2 (&z)[16]) {
    const float S = (float)SGN;
    const float2 K1 = make_float2( 0.9238795325112867f, S * 0.3826834323650898f);
    const float2 K2 = make_float2( 0.7071067811865476f, S * 0.7071067811865476f);
    const float2 K3 = make_float2( 0.3826834323650898f, S * 0.9238795325112867f);
    const float2 K6 = make_float2(-0.7071067811865476f, S * 0.7071067811865476f);
    const float2 K9 = make_float2(-0.9238795325112867f, -S * 0.3826834323650898f);
    float2 u[16];
    {   // layer 1: DFT4 over x[i+4m] -> u[4i+m], internal twiddle K[(i*m)&15]
        float2 y0, y1, y2, y3;
        dft4<SGN>(x[0], x[4], x[8],  x[12], y0, y1, y2, y3);
        u[0]=y0; u[1]=y1; u[2]=y2; u[3]=y3;
        dft4<SGN>(x[1], x[5], x[9],  x[13], y0, y1, y2, y3);
        u[4]=y0; u[5]=cmul(y1,K1); u[6]=cmul(y2,K2); u[7]=cmul(y3,K3);
        dft4<SGN>(x[2], x[6], x[10], x[14], y0, y1, y2, y3);
        u[8]=y0; u[9]=cmul(y1,K2);
        u[10]=make_float2(-S*y2.y, S*y2.x);           // * e^{SGN*pi i/2}
        u[11]=cmul(y3,K6);
        dft4<SGN>(x[3], x[7], x[11], x[15], y0, y1, y2, y3);
        u[12]=y0; u[13]=cmul(y1,K3); u[14]=cmul(y2,K6); u[15]=cmul(y3,K9);
    }
    // external twiddle powers
    float2 w2 = cmul(w,  w);
    float2 w3 = cmul(w2, w);
    float2 w4 = cmul(w2, w2);
    float2 w8 = cmul(w4, w4);
    float2 w12 = cmul(w8, w4);
    // layer 2: DFT4 over u[i+4m] -> out m at slot i+4m, * w4^m * wl^i
#pragma unroll
    for (int i = 0; i < 4; ++i) {
        float2 y0, y1, y2, y3;
        dft4<SGN>(u[i], u[i+4], u[i+8], u[i+12], y0, y1, y2, y3);
        float2 t1 = cmul(y1, w4), t2 = cmul(y2, w8), t3 = cmul(y3, w12);
        if (i == 0) { z[0] = y0; z[4] = t1; z[8] = t2; z[12] = t3; }
        else {
            float2 wl = (i == 1) ? w : ((i == 2) ? w2 : w3);
            z[i]      = cmul(y0, wl);
            z[i + 4]  = cmul(t1, wl);
            z[i + 8]  = cmul(t2, wl);
            z[i + 12] = cmul(t3, wl);
        }
    }
}

// Generic LDS->LDS radix-16 Stockham stage (wave-private). lane in [0,64).
template<int SGN, int S>
__device__ __forceinline__ void stage16(const float2* __restrict__ src,
                                        float2* __restrict__ dst,
                                        const float2* __restrict__ twl,
                                        int lane) {
    const int p = lane / S;
    const int q = lane - p * S;
    float2 x[16];
#pragma unroll
    for (int m = 0; m < 16; ++m) x[m] = src[P(lane + 64 * m)];
    float2 w = twl[S * p];
    if (SGN > 0) w.y = -w.y;
    float2 z[16];
    dft16_tw<SGN>(x, w, z);
#pragma unroll
    for (int m = 0; m < 16; ++m) dst[P(q + 16 * S * p + S * m)] = z[m];
}

// Final radix-4 stage (s=256): twiddle-free, in-place (wave-private).
template<int SGN>
__device__ __forceinline__ void stage4(float2* __restrict__ buf, int lt) {
#pragma unroll
    for (int r = 0; r < 4; ++r) {
        int i = lt + 64 * r;
        float2 a = buf[P(i)], b = buf[P(i + 256)], c = buf[P(i + 512)], d = buf[P(i + 768)];
        float2 y0, y1, y2, y3;
        dft4<SGN>(a, b, c, d, y0, y1, y2, y3);
        buf[P(i)]       = y0;
        buf[P(i + 256)] = y1;
        buf[P(i + 512)] = y2;
        buf[P(i + 768)] = y3;
    }
}

__global__ __launch_bounds__(512) void stft_chain_kernel(
    const float* __restrict__ transfer,
    const float* __restrict__ gainp,
    float* __restrict__ io)
{
    __shared__ float2 bufs[2][FCHUNK][BUFSZ];   // 139.3 KB ping-pong
    __shared__ float2 tailbuf[2][512];          // 8 KB raw chunk-crossing tail
    __shared__ float2 twl[64];                  // 0.5 KB e^{-2pi i j/1024}, j<64
    __shared__ float2 win2[512];                // 4 KB (win(2m), win(2m+1))

    const int bd  = blockIdx.x;        // 0..255
    const int d   = bd & 63;
    const int tid = threadIdx.x;       // 0..511
    const int lf  = tid >> 6;          // frame within chunk (0..7) == wave id
    const int lt  = tid & 63;          // lane within that frame's FFT
    const float g = gainp[0];
    const size_t base = (size_t)bd * TIME_N;
    const float PI  = 3.14159265358979323846f;
    const float PI2 = 6.2831853071795864769f;
    const float inv = 1.0f / 1024.0f;

    // --- persistent per-thread state: bin pair (tid, 1024-tid) + 512 on t0 ---
    const int kb = (tid == 0) ? 1024 : 1024 - tid;
    const float T0 = transfer[(size_t)d * NBINS + tid];
    const float T1 = transfer[(size_t)d * NBINS + kb];
    const float T5 = (tid == 0) ? transfer[(size_t)d * NBINS + 512] : 0.f;
    float2 C0 = make_float2(0.f, 0.f);
    float2 C1 = make_float2(0.f, 0.f);
    float2 C5 = make_float2(0.f, 0.f);
    float sHt, cHt; __sincosf((PI / HALFN) * (float)tid, &sHt, &cHt);

    // one-time LDS init
    tailbuf[0][tid] = make_float2(0.f, 0.f);
    tailbuf[1][tid] = make_float2(0.f, 0.f);
    if (tid < 64) {
        float s_, c_; __sincosf(-(PI2 / 1024.0f) * (float)tid, &s_, &c_);
        twl[tid] = make_float2(c_, s_);
    }
    {
        const float cd = __cosf(PI / 1024.0f);
        const float sd = __sinf(PI / 1024.0f);
        float s0, c0; __sincosf((PI / 512.0f) * (float)tid, &s0, &c0);
        float c1 = c0 * cd - s0 * sd;
        win2[tid] = make_float2(0.5f - 0.5f * c0, 0.5f - 0.5f * c1);
    }
    __syncthreads();

    for (int ch = 0; ch < NCHUNK; ++ch) {
        const int par = ch & 1;

        // ---- fwd stage A (s=1): fused global load + window + DFT16 ----
        {
            const int tb = (ch * FCHUNK + lf) * HALFN;
            float2 x[16];
#pragma unroll
            for (int m = 0; m < 16; ++m) {
                int n = lt + 64 * m;               // complex slot 0..1023
                int t = tb + 2 * n;
                float2 v = make_float2(0.f, 0.f);
                if (t < TIME_N)
                    v = *reinterpret_cast<const float2*>(io + base + t);
                float2 wv;
                if (m < 8) wv = win2[n];
                else { float2 ww = win2[n - 512]; wv = make_float2(1.f - ww.x, 1.f - ww.y); }
                x[m] = make_float2(v.x * wv.x, v.y * wv.y);
            }
            float2 w = twl[lt];
            float2 z[16];
            dft16_tw<-1>(x, w, z);
            float2* dst = &bufs[0][lf][0];
#pragma unroll
            for (int m = 0; m < 16; ++m) dst[P(16 * lt + m)] = z[m];
        }
        // ---- fwd stage B (s=16) + stage C (in-place) -> bufs[1] ----
        stage16<-1, 16>(&bufs[0][lf][0], &bufs[1][lf][0], twl, lt);
        stage4<-1>(&bufs[1][lf][0], lt);

        __syncthreads();   // #1: all frames' Z ready

        // ---- FUSED rfft-post + scan + irfft-pre, in-place on bufs[1] ----
        {
            float2 Zk = bufs[1][0][P(tid)];
            float2 Zn = bufs[1][0][P((HALFN - tid) & (HALFN - 1))];
#pragma unroll 2
            for (int f = 0; f < FCHUNK; ++f) {
                float2 Zk_n, Zn_n;
                if (f < FCHUNK - 1) {
                    Zk_n = bufs[1][f + 1][P(tid)];
                    Zn_n = bufs[1][f + 1][P((HALFN - tid) & (HALFN - 1))];
                }
                float2 Fe = make_float2(0.5f * (Zk.x + Zn.x), 0.5f * (Zk.y - Zn.y));
                float2 Fo = make_float2(0.5f * (Zk.y + Zn.y), -0.5f * (Zk.x - Zn.x));
                float2 U  = cmul(make_float2(cHt, -sHt), Fo);
                C0.x = (Fe.x + U.x + C0.x) * T0;
                C0.y = (Fe.y + U.y + C0.y) * T0;
                C1.x = (Fe.x - U.x + C1.x) * T1;
                C1.y = (U.y - Fe.y + C1.y) * T1;
                float2 Fe2 = make_float2(0.5f * (C0.x + C1.x), 0.5f * (C0.y - C1.y));
                float2 num = make_float2(0.5f * (C0.x - C1.x), 0.5f * (C0.y + C1.y));
                float2 Fo2 = cmul(make_float2(cHt, sHt), num);
                bufs[1][f][P(tid)] = make_float2(Fe2.x - Fo2.y, Fe2.y + Fo2.x);
                if (tid != 0) {
                    bufs[1][f][P(HALFN - tid)] =
                        make_float2(Fe2.x + Fo2.y, Fo2.x - Fe2.y);
                } else {
                    float2 Z5 = bufs[1][f][P(512)];
                    C5.x = ( Z5.x + C5.x) * T5;
                    C5.y = (-Z5.y + C5.y) * T5;
                    bufs[1][f][P(512)] = make_float2(C5.x, -C5.y);
                }
                Zk = Zk_n; Zn = Zn_n;
            }
        }
        __syncthreads();   // #2: all Z' ready

        // ---- inverse FFT: A (s=1) -> bufs[0], B (s=16) -> bufs[1], C in-place
        stage16<1, 1>(&bufs[1][lf][0], &bufs[0][lf][0], twl, lt);
        stage16<1, 16>(&bufs[0][lf][0], &bufs[1][lf][0], twl, lt);
        stage4<1>(&bufs[1][lf][0], lt);

        // ---- wave 7: stash raw second half for next chunk ----
        if (lf == 7) {
#pragma unroll 2
            for (int j = 0; j < 8; ++j) {
                int m = lt + 64 * j;                   // 0..511
                tailbuf[par][m] = bufs[1][7][P(m + 512)];
            }
        }
        __syncthreads();   // #3: inverse results + tail ready

        // ---- phase B: OLA (own first half + prev raw second half w/ 1-w),
        //      gain + tanh, store ----
        {
            const int tb = (ch * FCHUNK + lf) * HALFN;
#pragma unroll 2
            for (int j = 0; j < 8; ++j) {
                int m = lt + 64 * j;                   // 0..511
                float2 z  = bufs[1][lf][P(m)];
                float2 zp = (lf == 0) ? tailbuf[par ^ 1][m]
                                      : bufs[1][lf - 1][P(m + 512)];
                float2 wf = win2[m];
                float y0 = inv * (z.x * wf.x + zp.x * (1.f - wf.x));
                float y1 = inv * (z.y * wf.y + zp.y * (1.f - wf.y));
                float2 o = make_float2(ftanh(g * y0), ftanh(g * y1));
                *reinterpret_cast<float2*>(io + base + tb + 2 * m) = o;
            }
        }
        __syncthreads();   // #4: protect bufs[1] before next chunk's overwrite
    }
}

// ---------------------------------------------------------------------------
extern "C" void kernel_launch(void* const* d_in, const int* in_sizes, int n_in,
                              void* d_out, int out_size, void* d_ws, size_t ws_size,
                              hipStream_t stream) {
    const float* x        = (const float*)d_in[0];   // (4,64,65536)
    const float* transfer = (const float*)d_in[1];   // (64,1025)
    const float* mixer    = (const float*)d_in[2];   // (64,64)
    const float* gain     = (const float*)d_in[3];   // (1,)
    float* out = (float*)d_out;                      // (4,64,65536)

    dim3 g1(TIME_N / TT, 4);
    mix_kernel<<<g1, 256, 0, stream>>>(x, mixer, out);

    stft_chain_kernel<<<256, 512, 0, stream>>>(transfer, gain, out);
}

// Round 13
// 134.096 us; speedup vs baseline: 3.2857x; 1.0201x over previous
//
#include <hip/hip_runtime.h>
#include <math.h>

#define TIME_N 65536
#define HALFN  1024
#define NBINS  1025
#define NFRAMES 64
#define FCHUNK 16
#define NCHUNK (NFRAMES / FCHUNK)   // 4

// ---------------------------------------------------------------------------
// Kernel 1: channel mixing  out[b,d,t] = sum_c x[b,c,t] * M[c,d]
// ---------------------------------------------------------------------------
#define TT 128
__global__ __launch_bounds__(256) void mix_kernel(const float* __restrict__ x,
                                                  const float* __restrict__ M,
                                                  float* __restrict__ out) {
    __shared__ float Ml[64 * 64];
    __shared__ float xt[64][136];
    const int b   = blockIdx.y;
    const int t0  = blockIdx.x * TT;
    const int tid = threadIdx.x;

    for (int i = tid; i < 64 * 64; i += 256) Ml[i] = M[i];

    for (int r = 0; r < 8; ++r) {
        int fi = tid + r * 256;
        int c  = fi >> 5;
        int t4 = fi & 31;
        float4 v = *reinterpret_cast<const float4*>(
            x + (size_t)(b * 64 + c) * TIME_N + t0 + t4 * 4);
        *reinterpret_cast<float4*>(&xt[c][t4 * 4]) = v;
    }
    __syncthreads();

    const int dq = tid >> 5;
    const int tq = tid & 31;

    float acc[8][4];
#pragma unroll
    for (int i = 0; i < 8; ++i)
#pragma unroll
        for (int j = 0; j < 4; ++j) acc[i][j] = 0.f;

    for (int c = 0; c < 64; ++c) {
        float xv[4];
#pragma unroll
        for (int j = 0; j < 4; ++j) xv[j] = xt[c][tq + 32 * j];
#pragma unroll
        for (int i = 0; i < 8; ++i) {
            float mv = Ml[c * 64 + dq * 8 + i];
#pragma unroll
            for (int j = 0; j < 4; ++j) acc[i][j] += xv[j] * mv;
        }
    }

#pragma unroll
    for (int i = 0; i < 8; ++i) {
        int d = dq * 8 + i;
        size_t baseo = (size_t)(b * 64 + d) * TIME_N + t0;
#pragma unroll
        for (int j = 0; j < 4; ++j) out[baseo + tq + 32 * j] = acc[i][j];
    }
}

// ---------------------------------------------------------------------------
// Kernel 2: fused STFT -> per-bin frame recursion -> iSTFT -> OLA -> tanh.
// R12 math with IN-PLACE wave-private FFT stages (safe: every dft output
// depends on all of the lane's inputs, so all ds_reads precede ds_writes in
// wave-lockstep program order; zero-cost asm fence as insurance). Single
// buffer -> FCHUNK=16 frames/chunk in the same 152 KB -> 4 chunks, 4 barriers
// each = 16 barrier regions total (vs 32 in R12). Each wave owns 2 frames.
// ---------------------------------------------------------------------------
__device__ __forceinline__ int P(int i) { return i + (i >> 4); }   // pad-16
#define BUFSZ 1088   // P(1023) = 1086

__device__ __forceinline__ float2 cadd(float2 a, float2 b){return make_float2(a.x+b.x, a.y+b.y);}
__device__ __forceinline__ float2 csub(float2 a, float2 b){return make_float2(a.x-b.x, a.y-b.y);}
__device__ __forceinline__ float2 cmul(float2 a, float2 b){return make_float2(a.x*b.x - a.y*b.y, a.x*b.y + a.y*b.x);}

__device__ __forceinline__ float ftanh(float x) {
    float ax = fabsf(x);
    float e  = __expf(-2.0f * ax);
    float t  = (1.0f - e) * __builtin_amdgcn_rcpf(1.0f + e);
    return copysignf(t, x);
}

// DFT4 (no twiddles): X_m with kernel e^{SGN*2pi i mk/4}
template<int SGN>
__device__ __forceinline__ void dft4(float2 x0, float2 x1, float2 x2, float2 x3,
                                     float2& y0, float2& y1, float2& y2, float2& y3) {
    float2 apc = cadd(x0, x2), amc = csub(x0, x2);
    float2 bpd = cadd(x1, x3), bmd = csub(x1, x3);
    float2 sj  = make_float2(-(float)SGN * bmd.y, (float)SGN * bmd.x);  // SGN*j*bmd
    y0 = cadd(apc, bpd);
    y1 = cadd(amc, sj);
    y2 = csub(apc, bpd);
    y3 = csub(amc, sj);
}

// z[j] = DFT16(x)[j] * w^j  (kernel e^{SGN*2pi i jk/16}; w = ext twiddle base)
template<int SGN>
__device__ __forceinline__ void dft16_tw(const float2 (&x)[16], float2 w, float2 (&z)[16]) {
    const float S = (float)SGN;
    const float2 K1 = make_float2( 0.9238795325112867f, S * 0.3826834323650898f);
    const float2 K2 = make_float2( 0.7071067811865476f, S * 0.7071067811865476f);
    const float2 K3 = make_float2( 0.3826834323650898f, S * 0.9238795325112867f);
    const float2 K6 = make_float2(-0.7071067811865476f, S * 0.7071067811865476f);
    const float2 K9 = make_float2(-0.9238795325112867f, -S * 0.3826834323650898f);
    float2 u[16];
    {   // layer 1: DFT4 over x[i+4m] -> u[4i+m], internal twiddle K[(i*m)&15]
        float2 y0, y1, y2, y3;
        dft4<SGN>(x[0], x[4], x[8],  x[12], y0, y1, y2, y3);
        u[0]=y0; u[1]=y1; u[2]=y2; u[3]=y3;
        dft4<SGN>(x[1], x[5], x[9],  x[13], y0, y1, y2, y3);
        u[4]=y0; u[5]=cmul(y1,K1); u[6]=cmul(y2,K2); u[7]=cmul(y3,K3);
        dft4<SGN>(x[2], x[6], x[10], x[14], y0, y1, y2, y3);
        u[8]=y0; u[9]=cmul(y1,K2);
        u[10]=make_float2(-S*y2.y, S*y2.x);           // * e^{SGN*pi i/2}
        u[11]=cmul(y3,K6);
        dft4<SGN>(x[3], x[7], x[11], x[15], y0, y1, y2, y3);
        u[12]=y0; u[13]=cmul(y1,K3); u[14]=cmul(y2,K6); u[15]=cmul(y3,K9);
    }
    float2 w2 = cmul(w,  w);
    float2 w3 = cmul(w2, w);
    float2 w4 = cmul(w2, w2);
    float2 w8 = cmul(w4, w4);
    float2 w12 = cmul(w8, w4);
#pragma unroll
    for (int i = 0; i < 4; ++i) {
        float2 y0, y1, y2, y3;
        dft4<SGN>(u[i], u[i+4], u[i+8], u[i+12], y0, y1, y2, y3);
        float2 t1 = cmul(y1, w4), t2 = cmul(y2, w8), t3 = cmul(y3, w12);
        if (i == 0) { z[0] = y0; z[4] = t1; z[8] = t2; z[12] = t3; }
        else {
            float2 wl = (i == 1) ? w : ((i == 2) ? w2 : w3);
            z[i]      = cmul(y0, wl);
            z[i + 4]  = cmul(t1, wl);
            z[i + 8]  = cmul(t2, wl);
            z[i + 12] = cmul(t3, wl);
        }
    }
}

// IN-PLACE LDS radix-16 Stockham stage (wave-private). lane in [0,64).
// Safe in-place: all z depend on all x -> reads precede writes in wave order.
template<int SGN, int S>
__device__ __forceinline__ void stage16_ip(float2* __restrict__ b,
                                           const float2* __restrict__ twl,
                                           int lane) {
    const int p = lane / S;
    const int q = lane - p * S;
    float2 x[16];
#pragma unroll
    for (int m = 0; m < 16; ++m) x[m] = b[P(lane + 64 * m)];
    asm volatile("" ::: "memory");   // forbid store hoisting above loads
    float2 w = twl[S * p];
    if (SGN > 0) w.y = -w.y;
    float2 z[16];
    dft16_tw<SGN>(x, w, z);
#pragma unroll
    for (int m = 0; m < 16; ++m) b[P(q + 16 * S * p + S * m)] = z[m];
}

// Final radix-4 stage (s=256): twiddle-free, in-place (wave-private).
template<int SGN>
__device__ __forceinline__ void stage4_ip(float2* __restrict__ buf, int lt) {
#pragma unroll
    for (int r = 0; r < 4; ++r) {
        int i = lt + 64 * r;
        float2 a = buf[P(i)], b = buf[P(i + 256)], c = buf[P(i + 512)], d = buf[P(i + 768)];
        float2 y0, y1, y2, y3;
        dft4<SGN>(a, b, c, d, y0, y1, y2, y3);
        buf[P(i)]       = y0;
        buf[P(i + 256)] = y1;
        buf[P(i + 512)] = y2;
        buf[P(i + 768)] = y3;
    }
}

__global__ __launch_bounds__(512) void stft_chain_kernel(
    const float* __restrict__ transfer,
    const float* __restrict__ gainp,
    float* __restrict__ io)
{
    __shared__ float2 buf[FCHUNK][BUFSZ];       // 139.3 KB (single, in-place)
    __shared__ float2 tailbuf[2][512];          // 8 KB raw chunk-crossing tail
    __shared__ float2 twl[64];                  // 0.5 KB e^{-2pi i j/1024}
    __shared__ float2 win2[512];                // 4 KB (win(2m), win(2m+1))

    const int bd  = blockIdx.x;        // 0..255
    const int d   = bd & 63;
    const int tid = threadIdx.x;       // 0..511
    const int lf  = tid >> 6;          // wave id (0..7); owns frames 2lf, 2lf+1
    const int lt  = tid & 63;          // lane within wave
    const float g = gainp[0];
    const size_t base = (size_t)bd * TIME_N;
    const float PI  = 3.14159265358979323846f;
    const float PI2 = 6.2831853071795864769f;
    const float inv = 1.0f / 1024.0f;

    // --- persistent per-thread state: bin pair (tid, 1024-tid) + 512 on t0 ---
    const int kb = (tid == 0) ? 1024 : 1024 - tid;
    const float T0 = transfer[(size_t)d * NBINS + tid];
    const float T1 = transfer[(size_t)d * NBINS + kb];
    const float T5 = (tid == 0) ? transfer[(size_t)d * NBINS + 512] : 0.f;
    float2 C0 = make_float2(0.f, 0.f);
    float2 C1 = make_float2(0.f, 0.f);
    float2 C5 = make_float2(0.f, 0.f);
    float sHt, cHt; __sincosf((PI / HALFN) * (float)tid, &sHt, &cHt);

    // one-time LDS init
    tailbuf[0][tid] = make_float2(0.f, 0.f);
    tailbuf[1][tid] = make_float2(0.f, 0.f);
    if (tid < 64) {
        float s_, c_; __sincosf(-(PI2 / 1024.0f) * (float)tid, &s_, &c_);
        twl[tid] = make_float2(c_, s_);
    }
    {
        const float cd = __cosf(PI / 1024.0f);
        const float sd = __sinf(PI / 1024.0f);
        float s0, c0; __sincosf((PI / 512.0f) * (float)tid, &s0, &c0);
        float c1 = c0 * cd - s0 * sd;
        win2[tid] = make_float2(0.5f - 0.5f * c0, 0.5f - 0.5f * c1);
    }
    __syncthreads();

    for (int ch = 0; ch < NCHUNK; ++ch) {
        const int par = ch & 1;

        // ---- forward FFTs for both owned frames (wave-private, no barrier) --
#pragma unroll
        for (int fl = 0; fl < 2; ++fl) {
            const int f  = 2 * lf + fl;
            const int tb = (ch * FCHUNK + f) * HALFN;
            // stage A (s=1): fused global load + window + DFT16
            {
                float2 x[16];
#pragma unroll
                for (int m = 0; m < 16; ++m) {
                    int n = lt + 64 * m;               // complex slot 0..1023
                    int t = tb + 2 * n;
                    float2 v = make_float2(0.f, 0.f);
                    if (t < TIME_N)
                        v = *reinterpret_cast<const float2*>(io + base + t);
                    float2 wv;
                    if (m < 8) wv = win2[n];
                    else { float2 ww = win2[n - 512]; wv = make_float2(1.f - ww.x, 1.f - ww.y); }
                    x[m] = make_float2(v.x * wv.x, v.y * wv.y);
                }
                float2 w = twl[lt];
                float2 z[16];
                dft16_tw<-1>(x, w, z);
                float2* dst = &buf[f][0];
#pragma unroll
                for (int m = 0; m < 16; ++m) dst[P(16 * lt + m)] = z[m];
            }
            stage16_ip<-1, 16>(&buf[f][0], twl, lt);
            stage4_ip<-1>(&buf[f][0], lt);
        }
        __syncthreads();   // #1: all frames' Z ready

        // ---- FUSED rfft-post + scan + irfft-pre, in-place (16 frames) ----
        {
            float2 Zk = buf[0][P(tid)];
            float2 Zn = buf[0][P((HALFN - tid) & (HALFN - 1))];
#pragma unroll 2
            for (int f = 0; f < FCHUNK; ++f) {
                float2 Zk_n, Zn_n;
                if (f < FCHUNK - 1) {
                    Zk_n = buf[f + 1][P(tid)];
                    Zn_n = buf[f + 1][P((HALFN - tid) & (HALFN - 1))];
                }
                float2 Fe = make_float2(0.5f * (Zk.x + Zn.x), 0.5f * (Zk.y - Zn.y));
                float2 Fo = make_float2(0.5f * (Zk.y + Zn.y), -0.5f * (Zk.x - Zn.x));
                float2 U  = cmul(make_float2(cHt, -sHt), Fo);
                C0.x = (Fe.x + U.x + C0.x) * T0;
                C0.y = (Fe.y + U.y + C0.y) * T0;
                C1.x = (Fe.x - U.x + C1.x) * T1;
                C1.y = (U.y - Fe.y + C1.y) * T1;
                float2 Fe2 = make_float2(0.5f * (C0.x + C1.x), 0.5f * (C0.y - C1.y));
                float2 num = make_float2(0.5f * (C0.x - C1.x), 0.5f * (C0.y + C1.y));
                float2 Fo2 = cmul(make_float2(cHt, sHt), num);
                buf[f][P(tid)] = make_float2(Fe2.x - Fo2.y, Fe2.y + Fo2.x);
                if (tid != 0) {
                    buf[f][P(HALFN - tid)] =
                        make_float2(Fe2.x + Fo2.y, Fo2.x - Fe2.y);
                } else {
                    float2 Z5 = buf[f][P(512)];
                    C5.x = ( Z5.x + C5.x) * T5;
                    C5.y = (-Z5.y + C5.y) * T5;
                    buf[f][P(512)] = make_float2(C5.x, -C5.y);
                }
                Zk = Zk_n; Zn = Zn_n;
            }
        }
        __syncthreads();   // #2: all Z' ready

        // ---- inverse FFTs for both owned frames (wave-private) ----
#pragma unroll
        for (int fl = 0; fl < 2; ++fl) {
            const int f = 2 * lf + fl;
            stage16_ip<1, 1>(&buf[f][0], twl, lt);
            stage16_ip<1, 16>(&buf[f][0], twl, lt);
            stage4_ip<1>(&buf[f][0], lt);
        }

        // ---- wave 7: stash raw second half of frame 15 for next chunk ----
        if (lf == 7) {
#pragma unroll 2
            for (int j = 0; j < 8; ++j) {
                int m = lt + 64 * j;                   // 0..511
                tailbuf[par][m] = buf[FCHUNK - 1][P(m + 512)];
            }
        }
        __syncthreads();   // #3: inverse results + tail ready

        // ---- phase B: OLA + gain + tanh for both owned frames ----
#pragma unroll
        for (int fl = 0; fl < 2; ++fl) {
            const int f  = 2 * lf + fl;
            const int tb = (ch * FCHUNK + f) * HALFN;
#pragma unroll 2
            for (int j = 0; j < 8; ++j) {
                int m = lt + 64 * j;                   // 0..511
                float2 z  = buf[f][P(m)];
                float2 zp = (f == 0) ? tailbuf[par ^ 1][m]
                                     : buf[f - 1][P(m + 512)];
                float2 wf = win2[m];
                float y0 = inv * (z.x * wf.x + zp.x * (1.f - wf.x));
                float y1 = inv * (z.y * wf.y + zp.y * (1.f - wf.y));
                float2 o = make_float2(ftanh(g * y0), ftanh(g * y1));
                *reinterpret_cast<float2*>(io + base + tb + 2 * m) = o;
            }
        }
        __syncthreads();   // #4: protect buffers before next chunk's overwrite
    }
}

// ---------------------------------------------------------------------------
extern "C" void kernel_launch(void* const* d_in, const int* in_sizes, int n_in,
                              void* d_out, int out_size, void* d_ws, size_t ws_size,
                              hipStream_t stream) {
    const float* x        = (const float*)d_in[0];   // (4,64,65536)
    const float* transfer = (const float*)d_in[1];   // (64,1025)
    const float* mixer    = (const float*)d_in[2];   // (64,64)
    const float* gain     = (const float*)d_in[3];   // (1,)
    float* out = (float*)d_out;                      // (4,64,65536)

    dim3 g1(TIME_N / TT, 4);
    mix_kernel<<<g1, 256, 0, stream>>>(x, mixer, out);

    stft_chain_kernel<<<256, 512, 0, stream>>>(transfer, gain, out);
}

// Round 14
// 126.916 us; speedup vs baseline: 3.4716x; 1.0566x over previous
//
#include <hip/hip_runtime.h>
#include <math.h>

#define TIME_N 65536
#define HALFN  1024
#define NBINS  1025
#define NFRAMES 64
#define FCHUNK 16
#define NCHUNK (NFRAMES / FCHUNK)   // 4

// ---------------------------------------------------------------------------
// Kernel 1: channel mixing  out[b,d,t] = sum_c x[b,c,t] * M[c,d]
// ---------------------------------------------------------------------------
#define TT 128
__global__ __launch_bounds__(256) void mix_kernel(const float* __restrict__ x,
                                                  const float* __restrict__ M,
                                                  float* __restrict__ out) {
    __shared__ float Ml[64 * 64];
    __shared__ float xt[64][136];
    const int b   = blockIdx.y;
    const int t0  = blockIdx.x * TT;
    const int tid = threadIdx.x;

    for (int i = tid; i < 64 * 64; i += 256) Ml[i] = M[i];

    for (int r = 0; r < 8; ++r) {
        int fi = tid + r * 256;
        int c  = fi >> 5;
        int t4 = fi & 31;
        float4 v = *reinterpret_cast<const float4*>(
            x + (size_t)(b * 64 + c) * TIME_N + t0 + t4 * 4);
        *reinterpret_cast<float4*>(&xt[c][t4 * 4]) = v;
    }
    __syncthreads();

    const int dq = tid >> 5;
    const int tq = tid & 31;

    float acc[8][4];
#pragma unroll
    for (int i = 0; i < 8; ++i)
#pragma unroll
        for (int j = 0; j < 4; ++j) acc[i][j] = 0.f;

    for (int c = 0; c < 64; ++c) {
        float xv[4];
#pragma unroll
        for (int j = 0; j < 4; ++j) xv[j] = xt[c][tq + 32 * j];
#pragma unroll
        for (int i = 0; i < 8; ++i) {
            float mv = Ml[c * 64 + dq * 8 + i];
#pragma unroll
            for (int j = 0; j < 4; ++j) acc[i][j] += xv[j] * mv;
        }
    }

#pragma unroll
    for (int i = 0; i < 8; ++i) {
        int d = dq * 8 + i;
        size_t baseo = (size_t)(b * 64 + d) * TIME_N + t0;
#pragma unroll
        for (int j = 0; j < 4; ++j) out[baseo + tq + 32 * j] = acc[i][j];
    }
}

// ---------------------------------------------------------------------------
// Kernel 2: fused STFT -> per-bin frame recursion -> iSTFT -> OLA -> tanh.
// R13 structure (in-place wave-private radix-16 FFTs, FCHUNK=16, 16 barrier
// regions, fused conj-pair scan) + two VALU cuts:
//  * external twiddle-power sets (w,w2,w3,w4,w8,w12) hoisted to registers:
//    per-lane constant for both stage shapes (S=1: twl[lt]; S=16:
//    twl[16*(lt>>4)]); inverse applies conj via cmulc (same cost).
//  * asm memory fences removed (alias conservatism already orders in-place
//    same-buffer ops; the fence blocked cross-frame pipelining).
// ---------------------------------------------------------------------------
__device__ __forceinline__ int P(int i) { return i + (i >> 4); }   // pad-16
#define BUFSZ 1088   // P(1023) = 1086

__device__ __forceinline__ float2 cadd(float2 a, float2 b){return make_float2(a.x+b.x, a.y+b.y);}
__device__ __forceinline__ float2 csub(float2 a, float2 b){return make_float2(a.x-b.x, a.y-b.y);}
__device__ __forceinline__ float2 cmul(float2 a, float2 b){return make_float2(a.x*b.x - a.y*b.y, a.x*b.y + a.y*b.x);}

// SGN<0: a*w   SGN>0: a*conj(w)
template<int SGN>
__device__ __forceinline__ float2 cmul_s(float2 a, float2 w) {
    if (SGN < 0) return make_float2(a.x*w.x - a.y*w.y, a.x*w.y + a.y*w.x);
    else         return make_float2(a.x*w.x + a.y*w.y, a.y*w.x - a.x*w.y);
}

__device__ __forceinline__ float ftanh(float x) {
    float ax = fabsf(x);
    float e  = __expf(-2.0f * ax);
    float t  = (1.0f - e) * __builtin_amdgcn_rcpf(1.0f + e);
    return copysignf(t, x);
}

struct Tw16 { float2 w1, w2, w3, w4, w8, w12; };

// DFT4 (no twiddles): X_m with kernel e^{SGN*2pi i mk/4}
template<int SGN>
__device__ __forceinline__ void dft4(float2 x0, float2 x1, float2 x2, float2 x3,
                                     float2& y0, float2& y1, float2& y2, float2& y3) {
    float2 apc = cadd(x0, x2), amc = csub(x0, x2);
    float2 bpd = cadd(x1, x3), bmd = csub(x1, x3);
    float2 sj  = make_float2(-(float)SGN * bmd.y, (float)SGN * bmd.x);  // SGN*j*bmd
    y0 = cadd(apc, bpd);
    y1 = cadd(amc, sj);
    y2 = csub(apc, bpd);
    y3 = csub(amc, sj);
}

// z[j] = DFT16(x)[j] * w^j; w powers precomputed (fwd values; inv = conj).
template<int SGN>
__device__ __forceinline__ void dft16_tw(const float2 (&x)[16], const Tw16& tw,
                                         float2 (&z)[16]) {
    const float S = (float)SGN;
    const float2 K1 = make_float2( 0.9238795325112867f, S * 0.3826834323650898f);
    const float2 K2 = make_float2( 0.7071067811865476f, S * 0.7071067811865476f);
    const float2 K3 = make_float2( 0.3826834323650898f, S * 0.9238795325112867f);
    const float2 K6 = make_float2(-0.7071067811865476f, S * 0.7071067811865476f);
    const float2 K9 = make_float2(-0.9238795325112867f, -S * 0.3826834323650898f);
    float2 u[16];
    {   // layer 1: DFT4 over x[i+4m] -> u[4i+m], internal twiddle K[(i*m)&15]
        float2 y0, y1, y2, y3;
        dft4<SGN>(x[0], x[4], x[8],  x[12], y0, y1, y2, y3);
        u[0]=y0; u[1]=y1; u[2]=y2; u[3]=y3;
        dft4<SGN>(x[1], x[5], x[9],  x[13], y0, y1, y2, y3);
        u[4]=y0; u[5]=cmul(y1,K1); u[6]=cmul(y2,K2); u[7]=cmul(y3,K3);
        dft4<SGN>(x[2], x[6], x[10], x[14], y0, y1, y2, y3);
        u[8]=y0; u[9]=cmul(y1,K2);
        u[10]=make_float2(-S*y2.y, S*y2.x);           // * e^{SGN*pi i/2}
        u[11]=cmul(y3,K6);
        dft4<SGN>(x[3], x[7], x[11], x[15], y0, y1, y2, y3);
        u[12]=y0; u[13]=cmul(y1,K3); u[14]=cmul(y2,K6); u[15]=cmul(y3,K9);
    }
#pragma unroll
    for (int i = 0; i < 4; ++i) {
        float2 y0, y1, y2, y3;
        dft4<SGN>(u[i], u[i+4], u[i+8], u[i+12], y0, y1, y2, y3);
        float2 t1 = cmul_s<SGN>(y1, tw.w4);
        float2 t2 = cmul_s<SGN>(y2, tw.w8);
        float2 t3 = cmul_s<SGN>(y3, tw.w12);
        if (i == 0) { z[0] = y0; z[4] = t1; z[8] = t2; z[12] = t3; }
        else {
            float2 wl = (i == 1) ? tw.w1 : ((i == 2) ? tw.w2 : tw.w3);
            z[i]      = cmul_s<SGN>(y0, wl);
            z[i + 4]  = cmul_s<SGN>(t1, wl);
            z[i + 8]  = cmul_s<SGN>(t2, wl);
            z[i + 12] = cmul_s<SGN>(t3, wl);
        }
    }
}

// IN-PLACE LDS radix-16 Stockham stage (wave-private). lane in [0,64).
// In-place safety: all outputs depend on all inputs -> compiler alias
// conservatism keeps every ds_read before the (same-buffer) ds_writes.
template<int SGN, int S>
__device__ __forceinline__ void stage16_ip(float2* __restrict__ b,
                                           const Tw16& tw, int lane) {
    const int p = lane / S;
    const int q = lane - p * S;
    float2 x[16];
#pragma unroll
    for (int m = 0; m < 16; ++m) x[m] = b[P(lane + 64 * m)];
    float2 z[16];
    dft16_tw<SGN>(x, tw, z);
#pragma unroll
    for (int m = 0; m < 16; ++m) b[P(q + 16 * S * p + S * m)] = z[m];
}

// Final radix-4 stage (s=256): twiddle-free, in-place (wave-private).
template<int SGN>
__device__ __forceinline__ void stage4_ip(float2* __restrict__ buf, int lt) {
#pragma unroll
    for (int r = 0; r < 4; ++r) {
        int i = lt + 64 * r;
        float2 a = buf[P(i)], b = buf[P(i + 256)], c = buf[P(i + 512)], d = buf[P(i + 768)];
        float2 y0, y1, y2, y3;
        dft4<SGN>(a, b, c, d, y0, y1, y2, y3);
        buf[P(i)]       = y0;
        buf[P(i + 256)] = y1;
        buf[P(i + 512)] = y2;
        buf[P(i + 768)] = y3;
    }
}

__global__ __launch_bounds__(512) void stft_chain_kernel(
    const float* __restrict__ transfer,
    const float* __restrict__ gainp,
    float* __restrict__ io)
{
    __shared__ float2 buf[FCHUNK][BUFSZ];       // 139.3 KB (single, in-place)
    __shared__ float2 tailbuf[2][512];          // 8 KB raw chunk-crossing tail
    __shared__ float2 twl[64];                  // 0.5 KB e^{-2pi i j/1024}
    __shared__ float2 win2[512];                // 4 KB (win(2m), win(2m+1))

    const int bd  = blockIdx.x;        // 0..255
    const int d   = bd & 63;
    const int tid = threadIdx.x;       // 0..511
    const int lf  = tid >> 6;          // wave id (0..7); owns frames 2lf, 2lf+1
    const int lt  = tid & 63;          // lane within wave
    const float g = gainp[0];
    const size_t base = (size_t)bd * TIME_N;
    const float PI  = 3.14159265358979323846f;
    const float PI2 = 6.2831853071795864769f;
    const float inv = 1.0f / 1024.0f;

    // --- persistent per-thread state: bin pair (tid, 1024-tid) + 512 on t0 ---
    const int kb = (tid == 0) ? 1024 : 1024 - tid;
    const float T0 = transfer[(size_t)d * NBINS + tid];
    const float T1 = transfer[(size_t)d * NBINS + kb];
    const float T5 = (tid == 0) ? transfer[(size_t)d * NBINS + 512] : 0.f;
    float2 C0 = make_float2(0.f, 0.f);
    float2 C1 = make_float2(0.f, 0.f);
    float2 C5 = make_float2(0.f, 0.f);
    float sHt, cHt; __sincosf((PI / HALFN) * (float)tid, &sHt, &cHt);

    // one-time LDS init
    tailbuf[0][tid] = make_float2(0.f, 0.f);
    tailbuf[1][tid] = make_float2(0.f, 0.f);
    if (tid < 64) {
        float s_, c_; __sincosf(-(PI2 / 1024.0f) * (float)tid, &s_, &c_);
        twl[tid] = make_float2(c_, s_);
    }
    {
        const float cd = __cosf(PI / 1024.0f);
        const float sd = __sinf(PI / 1024.0f);
        float s0, c0; __sincosf((PI / 512.0f) * (float)tid, &s0, &c0);
        float c1 = c0 * cd - s0 * sd;
        win2[tid] = make_float2(0.5f - 0.5f * c0, 0.5f - 0.5f * c1);
    }
    __syncthreads();

    // --- hoisted external twiddle powers (per-lane constants, fwd values) ---
    Tw16 twA, twB;
    {
        float2 a = twl[lt];                  // stage shape S=1 base
        twA.w1 = a;
        twA.w2 = cmul(a, a);
        twA.w3 = cmul(twA.w2, a);
        twA.w4 = cmul(twA.w2, twA.w2);
        twA.w8 = cmul(twA.w4, twA.w4);
        twA.w12= cmul(twA.w8, twA.w4);
        float2 b = twl[16 * (lt >> 4)];      // stage shape S=16 base
        twB.w1 = b;
        twB.w2 = cmul(b, b);
        twB.w3 = cmul(twB.w2, b);
        twB.w4 = cmul(twB.w2, twB.w2);
        twB.w8 = cmul(twB.w4, twB.w4);
        twB.w12= cmul(twB.w8, twB.w4);
    }

    for (int ch = 0; ch < NCHUNK; ++ch) {
        const int par = ch & 1;

        // ---- forward FFTs for both owned frames (wave-private, no barrier) --
#pragma unroll
        for (int fl = 0; fl < 2; ++fl) {
            const int f  = 2 * lf + fl;
            const int tb = (ch * FCHUNK + f) * HALFN;
            // stage A (s=1): fused global load + window + DFT16
            {
                float2 x[16];
#pragma unroll
                for (int m = 0; m < 16; ++m) {
                    int n = lt + 64 * m;               // complex slot 0..1023
                    int t = tb + 2 * n;
                    float2 v = make_float2(0.f, 0.f);
                    if (t < TIME_N)
                        v = *reinterpret_cast<const float2*>(io + base + t);
                    float2 wv;
                    if (m < 8) wv = win2[n];
                    else { float2 ww = win2[n - 512]; wv = make_float2(1.f - ww.x, 1.f - ww.y); }
                    x[m] = make_float2(v.x * wv.x, v.y * wv.y);
                }
                float2 z[16];
                dft16_tw<-1>(x, twA, z);
                float2* dst = &buf[f][0];
#pragma unroll
                for (int m = 0; m < 16; ++m) dst[P(16 * lt + m)] = z[m];
            }
            stage16_ip<-1, 16>(&buf[f][0], twB, lt);
            stage4_ip<-1>(&buf[f][0], lt);
        }
        __syncthreads();   // #1: all frames' Z ready

        // ---- FUSED rfft-post + scan + irfft-pre, in-place (16 frames) ----
        {
            float2 Zk = buf[0][P(tid)];
            float2 Zn = buf[0][P((HALFN - tid) & (HALFN - 1))];
#pragma unroll 2
            for (int f = 0; f < FCHUNK; ++f) {
                float2 Zk_n, Zn_n;
                if (f < FCHUNK - 1) {
                    Zk_n = buf[f + 1][P(tid)];
                    Zn_n = buf[f + 1][P((HALFN - tid) & (HALFN - 1))];
                }
                float2 Fe = make_float2(0.5f * (Zk.x + Zn.x), 0.5f * (Zk.y - Zn.y));
                float2 Fo = make_float2(0.5f * (Zk.y + Zn.y), -0.5f * (Zk.x - Zn.x));
                float2 U  = cmul(make_float2(cHt, -sHt), Fo);
                C0.x = (Fe.x + U.x + C0.x) * T0;
                C0.y = (Fe.y + U.y + C0.y) * T0;
                C1.x = (Fe.x - U.x + C1.x) * T1;
                C1.y = (U.y - Fe.y + C1.y) * T1;
                float2 Fe2 = make_float2(0.5f * (C0.x + C1.x), 0.5f * (C0.y - C1.y));
                float2 num = make_float2(0.5f * (C0.x - C1.x), 0.5f * (C0.y + C1.y));
                float2 Fo2 = cmul(make_float2(cHt, sHt), num);
                buf[f][P(tid)] = make_float2(Fe2.x - Fo2.y, Fe2.y + Fo2.x);
                if (tid != 0) {
                    buf[f][P(HALFN - tid)] =
                        make_float2(Fe2.x + Fo2.y, Fo2.x - Fe2.y);
                } else {
                    float2 Z5 = buf[f][P(512)];
                    C5.x = ( Z5.x + C5.x) * T5;
                    C5.y = (-Z5.y + C5.y) * T5;
                    buf[f][P(512)] = make_float2(C5.x, -C5.y);
                }
                Zk = Zk_n; Zn = Zn_n;
            }
        }
        __syncthreads();   // #2: all Z' ready

        // ---- inverse FFTs for both owned frames (wave-private) ----
#pragma unroll
        for (int fl = 0; fl < 2; ++fl) {
            const int f = 2 * lf + fl;
            stage16_ip<1, 1>(&buf[f][0], twA, lt);
            stage16_ip<1, 16>(&buf[f][0], twB, lt);
            stage4_ip<1>(&buf[f][0], lt);
        }

        // ---- wave 7: stash raw second half of frame 15 for next chunk ----
        if (lf == 7) {
#pragma unroll 2
            for (int j = 0; j < 8; ++j) {
                int m = lt + 64 * j;                   // 0..511
                tailbuf[par][m] = buf[FCHUNK - 1][P(m + 512)];
            }
        }
        __syncthreads();   // #3: inverse results + tail ready

        // ---- phase B: OLA + gain + tanh for both owned frames ----
#pragma unroll
        for (int fl = 0; fl < 2; ++fl) {
            const int f  = 2 * lf + fl;
            const int tb = (ch * FCHUNK + f) * HALFN;
#pragma unroll 2
            for (int j = 0; j < 8; ++j) {
                int m = lt + 64 * j;                   // 0..511
                float2 z  = buf[f][P(m)];
                float2 zp = (f == 0) ? tailbuf[par ^ 1][m]
                                     : buf[f - 1][P(m + 512)];
                float2 wf = win2[m];
                float y0 = inv * (z.x * wf.x + zp.x * (1.f - wf.x));
                float y1 = inv * (z.y * wf.y + zp.y * (1.f - wf.y));
                float2 o = make_float2(ftanh(g * y0), ftanh(g * y1));
                *reinterpret_cast<float2*>(io + base + tb + 2 * m) = o;
            }
        }
        __syncthreads();   // #4: protect buffers before next chunk's overwrite
    }
}

// ---------------------------------------------------------------------------
extern "C" void kernel_launch(void* const* d_in, const int* in_sizes, int n_in,
                              void* d_out, int out_size, void* d_ws, size_t ws_size,
                              hipStream_t stream) {
    const float* x        = (const float*)d_in[0];   // (4,64,65536)
    const float* transfer = (const float*)d_in[1];   // (64,1025)
    const float* mixer    = (const float*)d_in[2];   // (64,64)
    const float* gain     = (const float*)d_in[3];   // (1,)
    float* out = (float*)d_out;                      // (4,64,65536)

    dim3 g1(TIME_N / TT, 4);
    mix_kernel<<<g1, 256, 0, stream>>>(x, mixer, out);

    stft_chain_kernel<<<256, 512, 0, stream>>>(transfer, gain, out);
}

// Round 15
// 116.495 us; speedup vs baseline: 3.7822x; 1.0895x over previous
//
#include <hip/hip_runtime.h>
#include <math.h>

#define TIME_N 65536
#define HALFN  1024
#define NBINS  1025
#define NFRAMES 64
#define FCHUNK 16
#define NCHUNK (NFRAMES / FCHUNK)   // 4

typedef float vf2 __attribute__((ext_vector_type(2)));

// ---------------------------------------------------------------------------
// Kernel 1: channel mixing  out[b,d,t] = sum_c x[b,c,t] * M[c,d]
// ---------------------------------------------------------------------------
#define TT 128
__global__ __launch_bounds__(256) void mix_kernel(const float* __restrict__ x,
                                                  const float* __restrict__ M,
                                                  float* __restrict__ out) {
    __shared__ float Ml[64 * 64];
    __shared__ float xt[64][136];
    const int b   = blockIdx.y;
    const int t0  = blockIdx.x * TT;
    const int tid = threadIdx.x;

    for (int i = tid; i < 64 * 64; i += 256) Ml[i] = M[i];

    for (int r = 0; r < 8; ++r) {
        int fi = tid + r * 256;
        int c  = fi >> 5;
        int t4 = fi & 31;
        float4 v = *reinterpret_cast<const float4*>(
            x + (size_t)(b * 64 + c) * TIME_N + t0 + t4 * 4);
        *reinterpret_cast<float4*>(&xt[c][t4 * 4]) = v;
    }
    __syncthreads();

    const int dq = tid >> 5;
    const int tq = tid & 31;

    float acc[8][4];
#pragma unroll
    for (int i = 0; i < 8; ++i)
#pragma unroll
        for (int j = 0; j < 4; ++j) acc[i][j] = 0.f;

    for (int c = 0; c < 64; ++c) {
        float xv[4];
#pragma unroll
        for (int j = 0; j < 4; ++j) xv[j] = xt[c][tq + 32 * j];
#pragma unroll
        for (int i = 0; i < 8; ++i) {
            float mv = Ml[c * 64 + dq * 8 + i];
#pragma unroll
            for (int j = 0; j < 4; ++j) acc[i][j] += xv[j] * mv;
        }
    }

#pragma unroll
    for (int i = 0; i < 8; ++i) {
        int d = dq * 8 + i;
        size_t baseo = (size_t)(b * 64 + d) * TIME_N + t0;
#pragma unroll
        for (int j = 0; j < 4; ++j) out[baseo + tq + 32 * j] = acc[i][j];
    }
}

// ---------------------------------------------------------------------------
// Kernel 2: fused STFT -> per-bin frame recursion -> iSTFT -> OLA -> tanh.
// R14 structure (in-place wave-private radix-16 FFTs, FCHUNK=16, 16 barrier
// regions, fused conj-pair scan, hoisted twiddle powers) with ALL complex
// arithmetic rewritten on ext_vector_type(2) float (vf2) in swizzle form so
// the backend emits packed VOP3P (v_pk_add/mul/fma_f32): cadd/csub 2->1
// inst, cmul 4->~2, sign/conj/mirror ops become packed sign-vector fmas.
// ---------------------------------------------------------------------------
__device__ __forceinline__ int P(int i) { return i + (i >> 4); }   // pad-16
#define BUFSZ 1088   // P(1023) = 1086

__device__ __forceinline__ vf2 cmul(vf2 a, vf2 b) {
    const vf2 ns = {-1.f, 1.f};
    return a.xx * b + ns * (a.yy * b.yx);
}
// a * conj(w)
__device__ __forceinline__ vf2 cmulc(vf2 a, vf2 w) {
    const vf2 ns = {1.f, -1.f};
    return w.xx * a + ns * (w.yy * a.yx);
}
template<int SGN>
__device__ __forceinline__ vf2 cmul_s(vf2 a, vf2 w) {
    if (SGN < 0) return cmul(a, w);
    else         return cmulc(a, w);
}

__device__ __forceinline__ float ftanh(float x) {
    float ax = fabsf(x);
    float e  = __expf(-2.0f * ax);
    float t  = (1.0f - e) * __builtin_amdgcn_rcpf(1.0f + e);
    return copysignf(t, x);
}

struct Tw16 { vf2 w1, w2, w3, w4, w8, w12; };

// DFT4 (no twiddles): X_m with kernel e^{SGN*2pi i mk/4}
template<int SGN>
__device__ __forceinline__ void dft4(vf2 x0, vf2 x1, vf2 x2, vf2 x3,
                                     vf2& y0, vf2& y1, vf2& y2, vf2& y3) {
    const vf2 nsj = {-(float)SGN, (float)SGN};
    vf2 apc = x0 + x2, amc = x0 - x2;
    vf2 bpd = x1 + x3, bmd = x1 - x3;
    vf2 sj  = nsj * bmd.yx;            // SGN*j*(x1-x3)
    y0 = apc + bpd;
    y1 = amc + sj;
    y2 = apc - bpd;
    y3 = amc - sj;
}

// z[j] = DFT16(x)[j] * w^j; w powers precomputed (fwd values; inv via conj).
template<int SGN>
__device__ __forceinline__ void dft16_tw(const vf2 (&x)[16], const Tw16& tw,
                                         vf2 (&z)[16]) {
    const float S = (float)SGN;
    const vf2 K1 = { 0.9238795325112867f, S * 0.3826834323650898f};
    const vf2 K2 = { 0.7071067811865476f, S * 0.7071067811865476f};
    const vf2 K3 = { 0.3826834323650898f, S * 0.9238795325112867f};
    const vf2 K6 = {-0.7071067811865476f, S * 0.7071067811865476f};
    const vf2 K9 = {-0.9238795325112867f, -S * 0.3826834323650898f};
    const vf2 nsj = {-S, S};
    vf2 u[16];
    {   // layer 1: DFT4 over x[i+4m] -> u[4i+m], internal twiddle K[(i*m)&15]
        vf2 y0, y1, y2, y3;
        dft4<SGN>(x[0], x[4], x[8],  x[12], y0, y1, y2, y3);
        u[0]=y0; u[1]=y1; u[2]=y2; u[3]=y3;
        dft4<SGN>(x[1], x[5], x[9],  x[13], y0, y1, y2, y3);
        u[4]=y0; u[5]=cmul(y1,K1); u[6]=cmul(y2,K2); u[7]=cmul(y3,K3);
        dft4<SGN>(x[2], x[6], x[10], x[14], y0, y1, y2, y3);
        u[8]=y0; u[9]=cmul(y1,K2);
        u[10]= nsj * y2.yx;                           // * e^{SGN*pi i/2}
        u[11]=cmul(y3,K6);
        dft4<SGN>(x[3], x[7], x[11], x[15], y0, y1, y2, y3);
        u[12]=y0; u[13]=cmul(y1,K3); u[14]=cmul(y2,K6); u[15]=cmul(y3,K9);
    }
#pragma unroll
    for (int i = 0; i < 4; ++i) {
        vf2 y0, y1, y2, y3;
        dft4<SGN>(u[i], u[i+4], u[i+8], u[i+12], y0, y1, y2, y3);
        vf2 t1 = cmul_s<SGN>(y1, tw.w4);
        vf2 t2 = cmul_s<SGN>(y2, tw.w8);
        vf2 t3 = cmul_s<SGN>(y3, tw.w12);
        if (i == 0) { z[0] = y0; z[4] = t1; z[8] = t2; z[12] = t3; }
        else {
            vf2 wl = (i == 1) ? tw.w1 : ((i == 2) ? tw.w2 : tw.w3);
            z[i]      = cmul_s<SGN>(y0, wl);
            z[i + 4]  = cmul_s<SGN>(t1, wl);
            z[i + 8]  = cmul_s<SGN>(t2, wl);
            z[i + 12] = cmul_s<SGN>(t3, wl);
        }
    }
}

// IN-PLACE LDS radix-16 Stockham stage (wave-private). lane in [0,64).
template<int SGN, int S>
__device__ __forceinline__ void stage16_ip(vf2* __restrict__ b,
                                           const Tw16& tw, int lane) {
    const int p = lane / S;
    const int q = lane - p * S;
    vf2 x[16];
#pragma unroll
    for (int m = 0; m < 16; ++m) x[m] = b[P(lane + 64 * m)];
    vf2 z[16];
    dft16_tw<SGN>(x, tw, z);
#pragma unroll
    for (int m = 0; m < 16; ++m) b[P(q + 16 * S * p + S * m)] = z[m];
}

// Final radix-4 stage (s=256): twiddle-free, in-place (wave-private).
template<int SGN>
__device__ __forceinline__ void stage4_ip(vf2* __restrict__ buf, int lt) {
#pragma unroll
    for (int r = 0; r < 4; ++r) {
        int i = lt + 64 * r;
        vf2 a = buf[P(i)], b = buf[P(i + 256)], c = buf[P(i + 512)], d = buf[P(i + 768)];
        vf2 y0, y1, y2, y3;
        dft4<SGN>(a, b, c, d, y0, y1, y2, y3);
        buf[P(i)]       = y0;
        buf[P(i + 256)] = y1;
        buf[P(i + 512)] = y2;
        buf[P(i + 768)] = y3;
    }
}

__global__ __launch_bounds__(512) void stft_chain_kernel(
    const float* __restrict__ transfer,
    const float* __restrict__ gainp,
    float* __restrict__ io)
{
    __shared__ vf2 buf[FCHUNK][BUFSZ];          // 139.3 KB (single, in-place)
    __shared__ vf2 tailbuf[2][512];             // 8 KB raw chunk-crossing tail
    __shared__ vf2 twl[64];                     // 0.5 KB e^{-2pi i j/1024}
    __shared__ vf2 win2[512];                   // 4 KB (win(2m), win(2m+1))

    const int bd  = blockIdx.x;        // 0..255
    const int d   = bd & 63;
    const int tid = threadIdx.x;       // 0..511
    const int lf  = tid >> 6;          // wave id (0..7); owns frames 2lf, 2lf+1
    const int lt  = tid & 63;          // lane within wave
    const float g = gainp[0];
    const size_t base = (size_t)bd * TIME_N;
    const float PI  = 3.14159265358979323846f;
    const float PI2 = 6.2831853071795864769f;
    const float inv = 1.0f / 1024.0f;
    const vf2 cj = {1.f, -1.f};
    const vf2 nm = {-1.f, 1.f};
    const vf2 one = {1.f, 1.f};

    // --- persistent per-thread state: bin pair (tid, 1024-tid) + 512 on t0 ---
    const int kb = (tid == 0) ? 1024 : 1024 - tid;
    const float T0 = transfer[(size_t)d * NBINS + tid];
    const float T1 = transfer[(size_t)d * NBINS + kb];
    const float T5 = (tid == 0) ? transfer[(size_t)d * NBINS + 512] : 0.f;
    vf2 C0 = {0.f, 0.f};
    vf2 C1 = {0.f, 0.f};
    vf2 C5 = {0.f, 0.f};
    float sHt, cHt; __sincosf((PI / HALFN) * (float)tid, &sHt, &cHt);
    const vf2 e2m = {cHt, -sHt};       // e^{-i pi k/1024}
    const vf2 e2p = {cHt,  sHt};       // e^{+i pi m/1024}

    // one-time LDS init
    tailbuf[0][tid] = (vf2){0.f, 0.f};
    tailbuf[1][tid] = (vf2){0.f, 0.f};
    if (tid < 64) {
        float s_, c_; __sincosf(-(PI2 / 1024.0f) * (float)tid, &s_, &c_);
        twl[tid] = (vf2){c_, s_};
    }
    {
        const float cd = __cosf(PI / 1024.0f);
        const float sd = __sinf(PI / 1024.0f);
        float s0, c0; __sincosf((PI / 512.0f) * (float)tid, &s0, &c0);
        float c1 = c0 * cd - s0 * sd;
        win2[tid] = (vf2){0.5f - 0.5f * c0, 0.5f - 0.5f * c1};
    }
    __syncthreads();

    // --- hoisted external twiddle powers (per-lane constants, fwd values) ---
    Tw16 twA, twB;
    {
        vf2 a = twl[lt];                  // stage shape S=1 base
        twA.w1 = a;
        twA.w2 = cmul(a, a);
        twA.w3 = cmul(twA.w2, a);
        twA.w4 = cmul(twA.w2, twA.w2);
        twA.w8 = cmul(twA.w4, twA.w4);
        twA.w12= cmul(twA.w8, twA.w4);
        vf2 b = twl[16 * (lt >> 4)];      // stage shape S=16 base
        twB.w1 = b;
        twB.w2 = cmul(b, b);
        twB.w3 = cmul(twB.w2, b);
        twB.w4 = cmul(twB.w2, twB.w2);
        twB.w8 = cmul(twB.w4, twB.w4);
        twB.w12= cmul(twB.w8, twB.w4);
    }

    for (int ch = 0; ch < NCHUNK; ++ch) {
        const int par = ch & 1;

        // ---- forward FFTs for both owned frames (wave-private, no barrier) --
#pragma unroll
        for (int fl = 0; fl < 2; ++fl) {
            const int f  = 2 * lf + fl;
            const int tb = (ch * FCHUNK + f) * HALFN;
            // stage A (s=1): fused global load + window + DFT16
            {
                vf2 x[16];
#pragma unroll
                for (int m = 0; m < 16; ++m) {
                    int n = lt + 64 * m;               // complex slot 0..1023
                    int t = tb + 2 * n;
                    vf2 v = {0.f, 0.f};
                    if (t < TIME_N)
                        v = *reinterpret_cast<const vf2*>(io + base + t);
                    vf2 wv;
                    if (m < 8) wv = win2[n];
                    else       wv = one - win2[n - 512];
                    x[m] = v * wv;
                }
                vf2 z[16];
                dft16_tw<-1>(x, twA, z);
                vf2* dst = &buf[f][0];
#pragma unroll
                for (int m = 0; m < 16; ++m) dst[P(16 * lt + m)] = z[m];
            }
            stage16_ip<-1, 16>(&buf[f][0], twB, lt);
            stage4_ip<-1>(&buf[f][0], lt);
        }
        __syncthreads();   // #1: all frames' Z ready

        // ---- FUSED rfft-post + scan + irfft-pre, in-place (16 frames) ----
        {
            vf2 Zk = buf[0][P(tid)];
            vf2 Zn = buf[0][P((HALFN - tid) & (HALFN - 1))];
#pragma unroll 2
            for (int f = 0; f < FCHUNK; ++f) {
                vf2 Zk_n, Zn_n;
                if (f < FCHUNK - 1) {
                    Zk_n = buf[f + 1][P(tid)];
                    Zn_n = buf[f + 1][P((HALFN - tid) & (HALFN - 1))];
                }
                vf2 Fe = 0.5f * (Zk + cj * Zn);        // (Zk.x+Zn.x, Zk.y-Zn.y)/2
                vf2 Fo = 0.5f * (cj * Zk.yx + Zn.yx);  // (Zk.y+Zn.y, -(Zk.x-Zn.x))/2
                vf2 U  = cmul(e2m, Fo);
                C0 = (Fe + U + C0) * T0;
                C1 = (cj * (Fe - U) + C1) * T1;
                vf2 Fe2 = 0.5f * (C0 + cj * C1);
                vf2 num = 0.5f * (C0 - cj * C1);
                vf2 Fo2 = cmul(e2p, num);
                buf[f][P(tid)] = Fe2 + nm * Fo2.yx;    // (Fe2.x-Fo2.y, Fe2.y+Fo2.x)
                if (tid != 0) {
                    buf[f][P(HALFN - tid)] = cj * Fe2 + Fo2.yx;
                } else {
                    vf2 Z5 = buf[f][P(512)];
                    C5 = (cj * Z5 + C5) * T5;
                    buf[f][P(512)] = cj * C5;
                }
                Zk = Zk_n; Zn = Zn_n;
            }
        }
        __syncthreads();   // #2: all Z' ready

        // ---- inverse FFTs for both owned frames (wave-private) ----
#pragma unroll
        for (int fl = 0; fl < 2; ++fl) {
            const int f = 2 * lf + fl;
            stage16_ip<1, 1>(&buf[f][0], twA, lt);
            stage16_ip<1, 16>(&buf[f][0], twB, lt);
            stage4_ip<1>(&buf[f][0], lt);
        }

        // ---- wave 7: stash raw second half of frame 15 for next chunk ----
        if (lf == 7) {
#pragma unroll 2
            for (int j = 0; j < 8; ++j) {
                int m = lt + 64 * j;                   // 0..511
                tailbuf[par][m] = buf[FCHUNK - 1][P(m + 512)];
            }
        }
        __syncthreads();   // #3: inverse results + tail ready

        // ---- phase B: OLA + gain + tanh for both owned frames ----
#pragma unroll
        for (int fl = 0; fl < 2; ++fl) {
            const int f  = 2 * lf + fl;
            const int tb = (ch * FCHUNK + f) * HALFN;
#pragma unroll 2
            for (int j = 0; j < 8; ++j) {
                int m = lt + 64 * j;                   // 0..511
                vf2 z  = buf[f][P(m)];
                vf2 zp = (f == 0) ? tailbuf[par ^ 1][m]
                                  : buf[f - 1][P(m + 512)];
                vf2 wf = win2[m];
                vf2 y  = (z * wf + zp * (one - wf)) * inv;
                vf2 o  = {ftanh(g * y.x), ftanh(g * y.y)};
                *reinterpret_cast<vf2*>(io + base + tb + 2 * m) = o;
            }
        }
        __syncthreads();   // #4: protect buffers before next chunk's overwrite
    }
}

// ---------------------------------------------------------------------------
extern "C" void kernel_launch(void* const* d_in, const int* in_sizes, int n_in,
                              void* d_out, int out_size, void* d_ws, size_t ws_size,
                              hipStream_t stream) {
    const float* x        = (const float*)d_in[0];   // (4,64,65536)
    const float* transfer = (const float*)d_in[1];   // (64,1025)
    const float* mixer    = (const float*)d_in[2];   // (64,64)
    const float* gain     = (const float*)d_in[3];   // (1,)
    float* out = (float*)d_out;                      // (4,64,65536)

    dim3 g1(TIME_N / TT, 4);
    mix_kernel<<<g1, 256, 0, stream>>>(x, mixer, out);

    stft_chain_kernel<<<256, 512, 0, stream>>>(transfer, gain, out);
}